// Round 2
// baseline (996.642 us; speedup 1.0000x reference)
//
#include <hip/hip_runtime.h>
#include <hip/hip_bf16.h>
#include <stdint.h>

#define N_NODES 100000
#define N_EDGES 1600000
#define IN_DIM 128
#define HID_DIM 128
#define OUT_DIM 64
#define NBUCKET 391   // ceil(N_NODES/256)

typedef __bf16 bf16x8 __attribute__((ext_vector_type(8)));
typedef float f32x4 __attribute__((ext_vector_type(4)));

__device__ __forceinline__ float bf16lo_f(uint32_t p) {
    return __uint_as_float(p << 16);
}
__device__ __forceinline__ float bf16hi_f(uint32_t p) {
    return __uint_as_float(p & 0xffff0000u);
}
__device__ __forceinline__ uint16_t f_to_bf16(float f) {
    uint32_t u = __float_as_uint(f);
    u += 0x7fffu + ((u >> 16) & 1u);   // round-to-nearest-even
    return (uint16_t)(u >> 16);
}

// ---------------- graph build ----------------

__global__ void zero_i32_k(int* __restrict__ p, int n) {
    int i = blockIdx.x * blockDim.x + threadIdx.x;
    if (i < n) p[i] = 0;
}

__global__ void hist_k(const int* __restrict__ dst, int* __restrict__ deg) {
    int e = blockIdx.x * blockDim.x + threadIdx.x;
    if (e < N_EDGES) atomicAdd(&deg[dst[e]], 1);
}

// block of 256 threads scans 1024 elements
__global__ void scan1_k(const int* __restrict__ deg, int* __restrict__ rowst,
                        int* __restrict__ partials) {
    __shared__ int sm[256];
    int tid = threadIdx.x;
    int base = blockIdx.x * 1024 + tid * 4;
    int v0 = 0, v1 = 0, v2 = 0, v3 = 0;
    if (base + 0 < N_NODES) v0 = deg[base + 0];
    if (base + 1 < N_NODES) v1 = deg[base + 1];
    if (base + 2 < N_NODES) v2 = deg[base + 2];
    if (base + 3 < N_NODES) v3 = deg[base + 3];
    int tot = v0 + v1 + v2 + v3;
    sm[tid] = tot;
    __syncthreads();
    int val = tot;
    for (int off = 1; off < 256; off <<= 1) {
        int x = (tid >= off) ? sm[tid - off] : 0;
        __syncthreads();
        val += x;
        sm[tid] = val;
        __syncthreads();
    }
    int excl = val - tot;
    if (tid == 255) partials[blockIdx.x] = val;
    if (base + 0 < N_NODES) rowst[base + 0] = excl;
    if (base + 1 < N_NODES) rowst[base + 1] = excl + v0;
    if (base + 2 < N_NODES) rowst[base + 2] = excl + v0 + v1;
    if (base + 3 < N_NODES) rowst[base + 3] = excl + v0 + v1 + v2;
}

#define NB_SCAN 98   // ceil(100000/1024)

__global__ void scan2_k(int* __restrict__ partials) {
    __shared__ int sm[128];
    int tid = threadIdx.x;
    int v = (tid < NB_SCAN) ? partials[tid] : 0;
    sm[tid] = v;
    __syncthreads();
    int val = v;
    for (int off = 1; off < 128; off <<= 1) {
        int x = (tid >= off) ? sm[tid - off] : 0;
        __syncthreads();
        val += x;
        sm[tid] = val;
        __syncthreads();
    }
    if (tid < NB_SCAN) partials[tid] = val - v;  // exclusive
}

// finalize rowst, write bucket cursors (bcur[b] = rowst[b*256]) and sentinel
__global__ void scan3_k(int* __restrict__ rowst, int* __restrict__ bcur,
                        const int* __restrict__ partials) {
    int i = blockIdx.x * blockDim.x + threadIdx.x;
    if (i < N_NODES) {
        int r = rowst[i] + partials[i >> 10];
        rowst[i] = r;
        if ((i & 255) == 0) bcur[i >> 8] = r;
    } else if (i == N_NODES) {
        rowst[N_NODES] = N_EDGES;   // sentinel
    }
}

// pass A: scatter packed (src<<8)|(dst&255) into per-bucket regions
__global__ void partition_k(const int* __restrict__ src, const int* __restrict__ dst,
                            int* __restrict__ bcur, uint32_t* __restrict__ packed) {
    int e = blockIdx.x * blockDim.x + threadIdx.x;
    if (e < N_EDGES) {
        int d = dst[e];
        int b = d >> 8;
        int pos = atomicAdd(&bcur[b], 1);
        packed[pos] = ((uint32_t)src[e] << 8) | (uint32_t)(d & 255);
    }
}

// pass B: per-bucket scatter in LDS, coalesced write-out
#define LCAP 6144   // bucket edge count: mean 4096, sigma ~64 -> 32 sigma headroom
__global__ __launch_bounds__(256) void bucket_k(const uint32_t* __restrict__ packed,
                                                const int* __restrict__ rowst,
                                                int* __restrict__ csr) {
    __shared__ int lcur[256];
    __shared__ int lcsr[LCAP];
    int b = blockIdx.x, t = threadIdx.x;
    int lo = b << 8;
    int hi = lo + 256; if (hi > N_NODES) hi = N_NODES;
    int base = rowst[lo];
    int cnt  = rowst[hi] - base;
    if (lo + t < hi) lcur[t] = rowst[lo + t] - base;
    __syncthreads();
    if (cnt <= LCAP) {
        for (int i = t; i < cnt; i += 256) {
            uint32_t pk = packed[base + i];
            int pos = atomicAdd(&lcur[pk & 255u], 1);
            lcsr[pos] = (int)(pk >> 8);
        }
        __syncthreads();
        for (int i = t; i < cnt; i += 256) csr[base + i] = lcsr[i];
    } else {  // safety fallback (statistically unreachable for uniform dst)
        for (int i = t; i < cnt; i += 256) {
            uint32_t pk = packed[base + i];
            int pos = atomicAdd(&lcur[pk & 255u], 1);
            csr[base + pos] = (int)(pk >> 8);
        }
    }
}

// ---------------- dtype prep ----------------

__global__ void cast_x_k(const float* __restrict__ x, uint16_t* __restrict__ xb) {
    int i = blockIdx.x * blockDim.x + threadIdx.x;  // one float4 per thread
    if (i < N_NODES * IN_DIM / 4) {
        const float4* xv = (const float4*)x;
        float4 v = xv[i];
        union { uint16_t u[4]; uint64_t q; } o;
        o.u[0] = f_to_bf16(v.x);
        o.u[1] = f_to_bf16(v.y);
        o.u[2] = f_to_bf16(v.z);
        o.u[3] = f_to_bf16(v.w);
        ((uint64_t*)xb)[i] = o.q;
    }
}

// wT1[n][k]: n<128, k<256 (k<128 -> W1l[k][n], else W1r[k-128][n])
// wT2[n][k]: n<128, k<128 (n<64 -> W2l[k][n], else W2r[k][n-64])
__global__ void prep_w_k(const float* __restrict__ W1l, const float* __restrict__ W1r,
                         const float* __restrict__ W2l, const float* __restrict__ W2r,
                         uint16_t* __restrict__ wT1, uint16_t* __restrict__ wT2) {
    int i = blockIdx.x * blockDim.x + threadIdx.x;
    if (i < 128 * 256) {
        int n = i >> 8, k = i & 255;
        float v = (k < 128) ? W1l[k * 128 + n] : W1r[(k - 128) * 128 + n];
        wT1[i] = f_to_bf16(v);
    } else {
        int j = i - 128 * 256;
        if (j < 128 * 128) {
            int n = j >> 7, k = j & 127;
            float v = (n < 64) ? W2l[k * 64 + n] : W2r[k * 64 + (n - 64)];
            wT2[j] = f_to_bf16(v);
        }
    }
}

// ---------------- mean aggregation, 128-dim (one wave per node) ----------------

__global__ void aggregate_k(const int* __restrict__ csr, const int* __restrict__ rowst,
                            const int* __restrict__ deg,
                            const uint32_t* __restrict__ in2, uint32_t* __restrict__ out2) {
    int gw = (blockIdx.x * blockDim.x + threadIdx.x) >> 6;
    int lane = threadIdx.x & 63;
    if (gw >= N_NODES) return;
    int start = rowst[gw];
    int d = deg[gw];
    float a0 = 0.f, a1 = 0.f;
    int j = 0;
    for (; j + 1 < d; j += 2) {
        int s0 = csr[start + j];
        int s1 = csr[start + j + 1];
        uint32_t p0 = in2[(size_t)s0 * 64 + lane];
        uint32_t p1 = in2[(size_t)s1 * 64 + lane];
        a0 += bf16lo_f(p0); a1 += bf16hi_f(p0);
        a0 += bf16lo_f(p1); a1 += bf16hi_f(p1);
    }
    if (j < d) {
        int s0 = csr[start + j];
        uint32_t p0 = in2[(size_t)s0 * 64 + lane];
        a0 += bf16lo_f(p0); a1 += bf16hi_f(p0);
    }
    float inv = 1.0f / (float)(d > 0 ? d : 1);
    a0 *= inv; a1 *= inv;
    uint32_t o = (uint32_t)f_to_bf16(a0) | ((uint32_t)f_to_bf16(a1) << 16);
    out2[(size_t)gw * 64 + lane] = o;
}

// ---------------- layer-1 GEMM: [aggr | x] (M x 256) @ wT1 (128 x 256)^T ----------------
// mfma_f32_16x16x32_bf16: A lane m=lane&15, k=quad*8+j ; B lane n=lane&15, k=quad*8+j
// C/D lane: col=lane&15, row=quad*4+reg   [m89-verified]

__global__ __launch_bounds__(256) void gemm1_k(const uint16_t* __restrict__ ab,
                                               const uint16_t* __restrict__ xb,
                                               const uint16_t* __restrict__ wT1,
                                               const float* __restrict__ b1,
                                               uint16_t* __restrict__ hb) {
    int wave = (blockIdx.x * 256 + threadIdx.x) >> 6;
    int lane = threadIdx.x & 63;
    int m0 = wave * 16;
    if (m0 >= N_NODES) return;
    int mr = lane & 15, quad = lane >> 4;

    const uint16_t* A1 = ab + (size_t)(m0 + mr) * 128 + quad * 8;
    const uint16_t* A2 = xb + (size_t)(m0 + mr) * 128 + quad * 8;

    f32x4 acc[8];
#pragma unroll
    for (int nt = 0; nt < 8; nt++) acc[nt] = (f32x4){0.f, 0.f, 0.f, 0.f};

#pragma unroll
    for (int kt = 0; kt < 8; kt++) {
        const uint16_t* ap = (kt < 4) ? (A1 + kt * 32) : (A2 + (kt - 4) * 32);
        bf16x8 a = *reinterpret_cast<const bf16x8*>(ap);
#pragma unroll
        for (int nt = 0; nt < 8; nt++) {
            const uint16_t* bp = wT1 + (size_t)(nt * 16 + mr) * 256 + kt * 32 + quad * 8;
            bf16x8 b = *reinterpret_cast<const bf16x8*>(bp);
            acc[nt] = __builtin_amdgcn_mfma_f32_16x16x32_bf16(a, b, acc[nt], 0, 0, 0);
        }
    }

#pragma unroll
    for (int nt = 0; nt < 8; nt++) {
        int col = nt * 16 + mr;
        float bias = b1[col];
#pragma unroll
        for (int r = 0; r < 4; r++) {
            int row = m0 + quad * 4 + r;
            float v = acc[nt][r] + bias;
            v = v > 0.f ? v : 0.f;
            hb[(size_t)row * 128 + col] = f_to_bf16(v);
        }
    }
}

// ---------------- layer-2 GEMM: h (M x 128) @ wT2 (128 x 128)^T ----------------
// cols 0..63  -> g  = h@W2l  (bf16, to be aggregated)
// cols 64..127-> z  = h@W2r + b2 (fp32)

__global__ __launch_bounds__(256) void gemm2_k(const uint16_t* __restrict__ hb,
                                               const uint16_t* __restrict__ wT2,
                                               const float* __restrict__ b2,
                                               uint16_t* __restrict__ g,
                                               float* __restrict__ z) {
    int wave = (blockIdx.x * 256 + threadIdx.x) >> 6;
    int lane = threadIdx.x & 63;
    int m0 = wave * 16;
    if (m0 >= N_NODES) return;
    int mr = lane & 15, quad = lane >> 4;

    const uint16_t* A = hb + (size_t)(m0 + mr) * 128 + quad * 8;

    f32x4 acc[8];
#pragma unroll
    for (int nt = 0; nt < 8; nt++) acc[nt] = (f32x4){0.f, 0.f, 0.f, 0.f};

#pragma unroll
    for (int kt = 0; kt < 4; kt++) {
        bf16x8 a = *reinterpret_cast<const bf16x8*>(A + kt * 32);
#pragma unroll
        for (int nt = 0; nt < 8; nt++) {
            const uint16_t* bp = wT2 + (size_t)(nt * 16 + mr) * 128 + kt * 32 + quad * 8;
            bf16x8 b = *reinterpret_cast<const bf16x8*>(bp);
            acc[nt] = __builtin_amdgcn_mfma_f32_16x16x32_bf16(a, b, acc[nt], 0, 0, 0);
        }
    }

#pragma unroll
    for (int nt = 0; nt < 8; nt++) {
        int col = nt * 16 + mr;
#pragma unroll
        for (int r = 0; r < 4; r++) {
            int row = m0 + quad * 4 + r;
            if (nt < 4) {
                g[(size_t)row * 64 + col] = f_to_bf16(acc[nt][r]);
            } else {
                z[(size_t)row * 64 + (col - 64)] = acc[nt][r] + b2[col - 64];
            }
        }
    }
}

// ---------------- layer-2 aggregation, 64-dim (one wave per node, 2 nbrs/step) ----

__global__ void agg2_k(const int* __restrict__ csr, const int* __restrict__ rowst,
                       const int* __restrict__ deg,
                       const uint32_t* __restrict__ g2, const float* __restrict__ z,
                       float* __restrict__ out) {
    int w = (blockIdx.x * blockDim.x + threadIdx.x) >> 6;
    int lane = threadIdx.x & 63;
    if (w >= N_NODES) return;
    int start = rowst[w];
    int d = deg[w];
    int c = lane & 31, p = lane >> 5;
    float a0 = 0.f, a1 = 0.f;
    int j = 0;
    for (; j + 3 < d; j += 4) {  // 4 neighbors per iteration (2 per half-wave)
        int s0 = csr[start + j + p];
        int s1 = csr[start + j + 2 + p];
        uint32_t q0 = g2[(size_t)s0 * 32 + c];
        uint32_t q1 = g2[(size_t)s1 * 32 + c];
        a0 += bf16lo_f(q0); a1 += bf16hi_f(q0);
        a0 += bf16lo_f(q1); a1 += bf16hi_f(q1);
    }
    for (; j + 1 < d; j += 2) {
        int s0 = csr[start + j + p];
        uint32_t q0 = g2[(size_t)s0 * 32 + c];
        a0 += bf16lo_f(q0); a1 += bf16hi_f(q0);
    }
    if (j < d && p == 0) {
        int s0 = csr[start + j];
        uint32_t q0 = g2[(size_t)s0 * 32 + c];
        a0 += bf16lo_f(q0); a1 += bf16hi_f(q0);
    }
    // combine the two half-wave partial sums
    a0 += __shfl_xor(a0, 32, 64);
    a1 += __shfl_xor(a1, 32, 64);
    if (lane < 32) {
        float inv = 1.0f / (float)(d > 0 ? d : 1);
        float2 zz = ((const float2*)z)[(size_t)w * 32 + c];
        float2 o;
        o.x = a0 * inv + zz.x;
        o.y = a1 * inv + zz.y;
        ((float2*)out)[(size_t)w * 32 + c] = o;
    }
}

// ---------------- launch ----------------

extern "C" void kernel_launch(void* const* d_in, const int* in_sizes, int n_in,
                              void* d_out, int out_size, void* d_ws, size_t ws_size,
                              hipStream_t stream) {
    const float* x   = (const float*)d_in[0];
    const int*  ei   = (const int*)d_in[1];
    const float* W1l = (const float*)d_in[2];
    const float* b1  = (const float*)d_in[3];
    const float* W1r = (const float*)d_in[4];
    const float* W2l = (const float*)d_in[5];
    const float* b2  = (const float*)d_in[6];
    const float* W2r = (const float*)d_in[7];
    float* out = (float*)d_out;

    const int* srcv = ei;            // edge_index[0]
    const int* dstv = ei + N_EDGES;  // edge_index[1]

    char* ws = (char*)d_ws;
    int*      deg      = (int*)(ws + 0);         // 100000 ints
    int*      rowst    = (int*)(ws + 401408);    // 100001 ints (sentinel)
    int*      bcur     = (int*)(ws + 802816);    // 391 ints
    int*      partials = (int*)(ws + 1204224);   // 98 ints
    int*      csr      = (int*)(ws + 1205248);   // 1.6M ints -> 7605248
    uint16_t* wT1      = (uint16_t*)(ws + 7605248);  // 64 KB -> 7670784
    uint16_t* wT2      = (uint16_t*)(ws + 7670784);  // 32 KB -> 7703552
    uint16_t* xb       = (uint16_t*)(ws + 7703552);  // 25.6 MB -> 33303552
    uint16_t* ab       = (uint16_t*)(ws + 33303552); // 25.6 MB -> 58903552
    uint16_t* hb       = (uint16_t*)(ws + 58903552); // 25.6 MB -> 84503552
    // aliases (stream-ordered, lifetimes disjoint):
    uint32_t* packed   = (uint32_t*)hb;   // 6.4 MB, consumed by bucket_k before hb written
    uint16_t* g        = xb;              // 12.8 MB, written by gemm2 after xb last read
    float*    z        = (float*)ab;      // 25.6 MB, written by gemm2 after ab last read

    // graph build
    zero_i32_k<<<391, 256, 0, stream>>>(deg, N_NODES);
    hist_k<<<6250, 256, 0, stream>>>(dstv, deg);
    scan1_k<<<NB_SCAN, 256, 0, stream>>>(deg, rowst, partials);
    scan2_k<<<1, 128, 0, stream>>>(partials);
    scan3_k<<<392, 256, 0, stream>>>(rowst, bcur, partials);
    partition_k<<<6250, 256, 0, stream>>>(srcv, dstv, bcur, packed);
    bucket_k<<<NBUCKET, 256, 0, stream>>>(packed, rowst, csr);

    // dtype prep
    cast_x_k<<<12500, 256, 0, stream>>>(x, xb);
    prep_w_k<<<192, 256, 0, stream>>>(W1l, W1r, W2l, W2r, wT1, wT2);

    // layer 1: aggr(x) -> ab ; h = relu([ab|x] @ wT1^T + b1) -> hb
    aggregate_k<<<25000, 256, 0, stream>>>(csr, rowst, deg, (const uint32_t*)xb, (uint32_t*)ab);
    gemm1_k<<<1563, 256, 0, stream>>>(ab, xb, wT1, b1, hb);

    // layer 2: [g|z] = h @ [W2l|W2r] (+b2 on z) ; out = mean-aggr(g) + z
    gemm2_k<<<1563, 256, 0, stream>>>(hb, wT2, b2, g, z);
    agg2_k<<<25000, 256, 0, stream>>>(csr, rowst, deg, (const uint32_t*)g, z, out);
}

// Round 3
// 397.568 us; speedup vs baseline: 2.5068x; 2.5068x over previous
//
#include <hip/hip_runtime.h>
#include <hip/hip_bf16.h>
#include <stdint.h>

#define N_NODES 100000
#define N_EDGES 1600000
#define IN_DIM 128
#define HID_DIM 128
#define OUT_DIM 64
#define NBUCKET 391   // ceil(N_NODES/256), bucket = dst>>8
#define NBE 391       // edge blocks, 4096 edges each
#define ECHUNK 4096
#define HM (NBUCKET * NBE)          // 152881 hist entries
#define NB_SCAN 150                 // ceil(HM/1024)

typedef __bf16 bf16x8 __attribute__((ext_vector_type(8)));
typedef float f32x4 __attribute__((ext_vector_type(4)));

__device__ __forceinline__ float bf16lo_f(uint32_t p) {
    return __uint_as_float(p << 16);
}
__device__ __forceinline__ float bf16hi_f(uint32_t p) {
    return __uint_as_float(p & 0xffff0000u);
}
__device__ __forceinline__ uint16_t f_to_bf16(float f) {
    uint32_t u = __float_as_uint(f);
    u += 0x7fffu + ((u >> 16) & 1u);   // round-to-nearest-even
    return (uint16_t)(u >> 16);
}

// ---------------- graph build: atomic-free two-pass radix partition ----------------

// pass 1: per-(block,bucket) histogram. LDS atomics only.
__global__ __launch_bounds__(256) void hist1_k(const int* __restrict__ dst,
                                               int* __restrict__ hist) {
    __shared__ int lh[NBUCKET];
    int blk = blockIdx.x, t = threadIdx.x;
    for (int i = t; i < NBUCKET; i += 256) lh[i] = 0;
    __syncthreads();
    int e0 = blk * ECHUNK;
    int e1 = e0 + ECHUNK; if (e1 > N_EDGES) e1 = N_EDGES;
    for (int e = e0 + t; e < e1; e += 256) atomicAdd(&lh[dst[e] >> 8], 1);
    __syncthreads();
    for (int i = t; i < NBUCKET; i += 256) hist[i * NBE + blk] = lh[i];
}

// generalized 3-level exclusive scan (in place), 1024 elems / block
__global__ void scan1_k(int* __restrict__ data, int* __restrict__ partials, int n) {
    __shared__ int sm[256];
    int tid = threadIdx.x;
    int base = blockIdx.x * 1024 + tid * 4;
    int v0 = 0, v1 = 0, v2 = 0, v3 = 0;
    if (base + 0 < n) v0 = data[base + 0];
    if (base + 1 < n) v1 = data[base + 1];
    if (base + 2 < n) v2 = data[base + 2];
    if (base + 3 < n) v3 = data[base + 3];
    int tot = v0 + v1 + v2 + v3;
    sm[tid] = tot;
    __syncthreads();
    int val = tot;
    for (int off = 1; off < 256; off <<= 1) {
        int x = (tid >= off) ? sm[tid - off] : 0;
        __syncthreads();
        val += x;
        sm[tid] = val;
        __syncthreads();
    }
    int excl = val - tot;
    if (tid == 255) partials[blockIdx.x] = val;
    if (base + 0 < n) data[base + 0] = excl;
    if (base + 1 < n) data[base + 1] = excl + v0;
    if (base + 2 < n) data[base + 2] = excl + v0 + v1;
    if (base + 3 < n) data[base + 3] = excl + v0 + v1 + v2;
}

__global__ void scan2_k(int* __restrict__ partials, int nb) {
    __shared__ int sm[256];
    int tid = threadIdx.x;
    int v = (tid < nb) ? partials[tid] : 0;
    sm[tid] = v;
    __syncthreads();
    int val = v;
    for (int off = 1; off < 256; off <<= 1) {
        int x = (tid >= off) ? sm[tid - off] : 0;
        __syncthreads();
        val += x;
        sm[tid] = val;
        __syncthreads();
    }
    if (tid < nb) partials[tid] = val - v;  // exclusive
}

__global__ void scan3_k(int* __restrict__ data, const int* __restrict__ partials, int n) {
    int i = blockIdx.x * blockDim.x + threadIdx.x;
    if (i < n) data[i] += partials[i >> 10];
}

// pass 2: rank via LDS cursors (seeded from this block's hoff column), write packed
__global__ __launch_bounds__(256) void scatter2_k(const int* __restrict__ src,
                                                  const int* __restrict__ dst,
                                                  const int* __restrict__ hoff,
                                                  uint32_t* __restrict__ packed) {
    __shared__ int loff[NBUCKET];
    int blk = blockIdx.x, t = threadIdx.x;
    for (int i = t; i < NBUCKET; i += 256) loff[i] = hoff[i * NBE + blk];
    __syncthreads();
    int e0 = blk * ECHUNK;
    int e1 = e0 + ECHUNK; if (e1 > N_EDGES) e1 = N_EDGES;
    for (int e = e0 + t; e < e1; e += 256) {
        int d = dst[e];
        int pos = atomicAdd(&loff[d >> 8], 1);
        packed[pos] = ((uint32_t)src[e] << 8) | (uint32_t)(d & 255);
    }
}

// pass 3: per-bucket CSR finalize in LDS; also emits deg[] and rowst[]
#define LCAP 6144   // bucket mean 4092, sigma ~64 -> 32 sigma headroom
__global__ __launch_bounds__(256) void bucket_k(const uint32_t* __restrict__ packed,
                                                const int* __restrict__ hoff,
                                                int* __restrict__ csr,
                                                int* __restrict__ deg,
                                                int* __restrict__ rowst) {
    __shared__ int lhist[256];
    __shared__ int lcur[256];
    __shared__ int ssc[256];
    __shared__ uint32_t lpk[LCAP];
    __shared__ int lcsr[LCAP];
    int b = blockIdx.x, t = threadIdx.x;
    int base = hoff[b * NBE];
    int next = (b + 1 < NBUCKET) ? hoff[(b + 1) * NBE] : N_EDGES;
    int cnt = next - base;
    lhist[t] = 0;
    __syncthreads();
    bool fit = (cnt <= LCAP);
    if (fit) {
        for (int i = t; i < cnt; i += 256) {
            uint32_t pk = packed[base + i];
            lpk[i] = pk;
            atomicAdd(&lhist[pk & 255u], 1);
        }
    } else {  // statistically unreachable safety path
        for (int i = t; i < cnt; i += 256) {
            uint32_t pk = packed[base + i];
            atomicAdd(&lhist[pk & 255u], 1);
        }
    }
    __syncthreads();
    int cl = lhist[t];
    ssc[t] = cl;
    __syncthreads();
    int val = cl;
    for (int off = 1; off < 256; off <<= 1) {
        int x = (t >= off) ? ssc[t - off] : 0;
        __syncthreads();
        val += x;
        ssc[t] = val;
        __syncthreads();
    }
    int excl = val - cl;
    lcur[t] = excl;
    int node = (b << 8) + t;
    if (node < N_NODES) { deg[node] = cl; rowst[node] = base + excl; }
    __syncthreads();
    if (fit) {
        for (int i = t; i < cnt; i += 256) {
            uint32_t pk = lpk[i];
            int pos = atomicAdd(&lcur[pk & 255u], 1);
            lcsr[pos] = (int)(pk >> 8);
        }
        __syncthreads();
        for (int i = t; i < cnt; i += 256) csr[base + i] = lcsr[i];
    } else {
        for (int i = t; i < cnt; i += 256) {
            uint32_t pk = packed[base + i];
            int pos = atomicAdd(&lcur[pk & 255u], 1);
            csr[base + pos] = (int)(pk >> 8);
        }
    }
}

// ---------------- dtype prep ----------------

__global__ void cast_x_k(const float* __restrict__ x, uint16_t* __restrict__ xb) {
    int i = blockIdx.x * blockDim.x + threadIdx.x;  // one float4 per thread
    if (i < N_NODES * IN_DIM / 4) {
        const float4* xv = (const float4*)x;
        float4 v = xv[i];
        union { uint16_t u[4]; uint64_t q; } o;
        o.u[0] = f_to_bf16(v.x);
        o.u[1] = f_to_bf16(v.y);
        o.u[2] = f_to_bf16(v.z);
        o.u[3] = f_to_bf16(v.w);
        ((uint64_t*)xb)[i] = o.q;
    }
}

// wT1[n][k]: n<128, k<256 (k<128 -> W1l[k][n], else W1r[k-128][n])
// wT2[n][k]: n<128, k<128 (n<64 -> W2l[k][n], else W2r[k][n-64])
__global__ void prep_w_k(const float* __restrict__ W1l, const float* __restrict__ W1r,
                         const float* __restrict__ W2l, const float* __restrict__ W2r,
                         uint16_t* __restrict__ wT1, uint16_t* __restrict__ wT2) {
    int i = blockIdx.x * blockDim.x + threadIdx.x;
    if (i < 128 * 256) {
        int n = i >> 8, k = i & 255;
        float v = (k < 128) ? W1l[k * 128 + n] : W1r[(k - 128) * 128 + n];
        wT1[i] = f_to_bf16(v);
    } else {
        int j = i - 128 * 256;
        if (j < 128 * 128) {
            int n = j >> 7, k = j & 127;
            float v = (n < 64) ? W2l[k * 64 + n] : W2r[k * 64 + (n - 64)];
            wT2[j] = f_to_bf16(v);
        }
    }
}

// ---------------- mean aggregation, 128-dim (one wave per node) ----------------

__global__ void aggregate_k(const int* __restrict__ csr, const int* __restrict__ rowst,
                            const int* __restrict__ deg,
                            const uint32_t* __restrict__ in2, uint32_t* __restrict__ out2) {
    int gw = (blockIdx.x * blockDim.x + threadIdx.x) >> 6;
    int lane = threadIdx.x & 63;
    if (gw >= N_NODES) return;
    int start = rowst[gw];
    int d = deg[gw];
    float a0 = 0.f, a1 = 0.f;
    int j = 0;
    for (; j + 1 < d; j += 2) {
        int s0 = csr[start + j];
        int s1 = csr[start + j + 1];
        uint32_t p0 = in2[(size_t)s0 * 64 + lane];
        uint32_t p1 = in2[(size_t)s1 * 64 + lane];
        a0 += bf16lo_f(p0); a1 += bf16hi_f(p0);
        a0 += bf16lo_f(p1); a1 += bf16hi_f(p1);
    }
    if (j < d) {
        int s0 = csr[start + j];
        uint32_t p0 = in2[(size_t)s0 * 64 + lane];
        a0 += bf16lo_f(p0); a1 += bf16hi_f(p0);
    }
    float inv = 1.0f / (float)(d > 0 ? d : 1);
    a0 *= inv; a1 *= inv;
    uint32_t o = (uint32_t)f_to_bf16(a0) | ((uint32_t)f_to_bf16(a1) << 16);
    out2[(size_t)gw * 64 + lane] = o;
}

// ---------------- layer-1 GEMM: [aggr | x] (M x 256) @ wT1 (128 x 256)^T ----------------
// mfma_f32_16x16x32_bf16: A lane m=lane&15, k=quad*8+j ; B lane n=lane&15, k=quad*8+j
// C/D lane: col=lane&15, row=quad*4+reg   [m89-verified]

__global__ __launch_bounds__(256) void gemm1_k(const uint16_t* __restrict__ ab,
                                               const uint16_t* __restrict__ xb,
                                               const uint16_t* __restrict__ wT1,
                                               const float* __restrict__ b1,
                                               uint16_t* __restrict__ hb) {
    int wave = (blockIdx.x * 256 + threadIdx.x) >> 6;
    int lane = threadIdx.x & 63;
    int m0 = wave * 16;
    if (m0 >= N_NODES) return;
    int mr = lane & 15, quad = lane >> 4;

    const uint16_t* A1 = ab + (size_t)(m0 + mr) * 128 + quad * 8;
    const uint16_t* A2 = xb + (size_t)(m0 + mr) * 128 + quad * 8;

    f32x4 acc[8];
#pragma unroll
    for (int nt = 0; nt < 8; nt++) acc[nt] = (f32x4){0.f, 0.f, 0.f, 0.f};

#pragma unroll
    for (int kt = 0; kt < 8; kt++) {
        const uint16_t* ap = (kt < 4) ? (A1 + kt * 32) : (A2 + (kt - 4) * 32);
        bf16x8 a = *reinterpret_cast<const bf16x8*>(ap);
#pragma unroll
        for (int nt = 0; nt < 8; nt++) {
            const uint16_t* bp = wT1 + (size_t)(nt * 16 + mr) * 256 + kt * 32 + quad * 8;
            bf16x8 b = *reinterpret_cast<const bf16x8*>(bp);
            acc[nt] = __builtin_amdgcn_mfma_f32_16x16x32_bf16(a, b, acc[nt], 0, 0, 0);
        }
    }

#pragma unroll
    for (int nt = 0; nt < 8; nt++) {
        int col = nt * 16 + mr;
        float bias = b1[col];
#pragma unroll
        for (int r = 0; r < 4; r++) {
            int row = m0 + quad * 4 + r;
            float v = acc[nt][r] + bias;
            v = v > 0.f ? v : 0.f;
            hb[(size_t)row * 128 + col] = f_to_bf16(v);
        }
    }
}

// ---------------- layer-2 GEMM: h (M x 128) @ wT2 (128 x 128)^T ----------------
// cols 0..63  -> g  = h@W2l  (bf16, to be aggregated)
// cols 64..127-> z  = h@W2r + b2 (fp32)

__global__ __launch_bounds__(256) void gemm2_k(const uint16_t* __restrict__ hb,
                                               const uint16_t* __restrict__ wT2,
                                               const float* __restrict__ b2,
                                               uint16_t* __restrict__ g,
                                               float* __restrict__ z) {
    int wave = (blockIdx.x * 256 + threadIdx.x) >> 6;
    int lane = threadIdx.x & 63;
    int m0 = wave * 16;
    if (m0 >= N_NODES) return;
    int mr = lane & 15, quad = lane >> 4;

    const uint16_t* A = hb + (size_t)(m0 + mr) * 128 + quad * 8;

    f32x4 acc[8];
#pragma unroll
    for (int nt = 0; nt < 8; nt++) acc[nt] = (f32x4){0.f, 0.f, 0.f, 0.f};

#pragma unroll
    for (int kt = 0; kt < 4; kt++) {
        bf16x8 a = *reinterpret_cast<const bf16x8*>(A + kt * 32);
#pragma unroll
        for (int nt = 0; nt < 8; nt++) {
            const uint16_t* bp = wT2 + (size_t)(nt * 16 + mr) * 128 + kt * 32 + quad * 8;
            bf16x8 b = *reinterpret_cast<const bf16x8*>(bp);
            acc[nt] = __builtin_amdgcn_mfma_f32_16x16x32_bf16(a, b, acc[nt], 0, 0, 0);
        }
    }

#pragma unroll
    for (int nt = 0; nt < 8; nt++) {
        int col = nt * 16 + mr;
#pragma unroll
        for (int r = 0; r < 4; r++) {
            int row = m0 + quad * 4 + r;
            if (nt < 4) {
                g[(size_t)row * 64 + col] = f_to_bf16(acc[nt][r]);
            } else {
                z[(size_t)row * 64 + (col - 64)] = acc[nt][r] + b2[col - 64];
            }
        }
    }
}

// ---------------- layer-2 aggregation, 64-dim (one wave per node) ----------------

__global__ void agg2_k(const int* __restrict__ csr, const int* __restrict__ rowst,
                       const int* __restrict__ deg,
                       const uint32_t* __restrict__ g2, const float* __restrict__ z,
                       float* __restrict__ out) {
    int w = (blockIdx.x * blockDim.x + threadIdx.x) >> 6;
    int lane = threadIdx.x & 63;
    if (w >= N_NODES) return;
    int start = rowst[w];
    int d = deg[w];
    int c = lane & 31, p = lane >> 5;
    float a0 = 0.f, a1 = 0.f;
    int j = 0;
    for (; j + 3 < d; j += 4) {  // 4 neighbors per iteration (2 per half-wave)
        int s0 = csr[start + j + p];
        int s1 = csr[start + j + 2 + p];
        uint32_t q0 = g2[(size_t)s0 * 32 + c];
        uint32_t q1 = g2[(size_t)s1 * 32 + c];
        a0 += bf16lo_f(q0); a1 += bf16hi_f(q0);
        a0 += bf16lo_f(q1); a1 += bf16hi_f(q1);
    }
    for (; j + 1 < d; j += 2) {
        int s0 = csr[start + j + p];
        uint32_t q0 = g2[(size_t)s0 * 32 + c];
        a0 += bf16lo_f(q0); a1 += bf16hi_f(q0);
    }
    if (j < d && p == 0) {
        int s0 = csr[start + j];
        uint32_t q0 = g2[(size_t)s0 * 32 + c];
        a0 += bf16lo_f(q0); a1 += bf16hi_f(q0);
    }
    a0 += __shfl_xor(a0, 32, 64);
    a1 += __shfl_xor(a1, 32, 64);
    if (lane < 32) {
        float inv = 1.0f / (float)(d > 0 ? d : 1);
        float2 zz = ((const float2*)z)[(size_t)w * 32 + c];
        float2 o;
        o.x = a0 * inv + zz.x;
        o.y = a1 * inv + zz.y;
        ((float2*)out)[(size_t)w * 32 + c] = o;
    }
}

// ---------------- launch ----------------

extern "C" void kernel_launch(void* const* d_in, const int* in_sizes, int n_in,
                              void* d_out, int out_size, void* d_ws, size_t ws_size,
                              hipStream_t stream) {
    const float* x   = (const float*)d_in[0];
    const int*  ei   = (const int*)d_in[1];
    const float* W1l = (const float*)d_in[2];
    const float* b1  = (const float*)d_in[3];
    const float* W1r = (const float*)d_in[4];
    const float* W2l = (const float*)d_in[5];
    const float* b2  = (const float*)d_in[6];
    const float* W2r = (const float*)d_in[7];
    float* out = (float*)d_out;

    const int* srcv = ei;            // edge_index[0]
    const int* dstv = ei + N_EDGES;  // edge_index[1]

    char* ws = (char*)d_ws;
    int*      deg      = (int*)(ws + 0);             // 100000 ints
    int*      rowst    = (int*)(ws + 401408);        // 100000 ints
    int*      partials = (int*)(ws + 802816);        // 150 ints
    int*      csr      = (int*)(ws + 1205248);       // 1.6M ints -> 7605248
    uint16_t* wT1      = (uint16_t*)(ws + 7605248);  // 64 KB -> 7670784
    uint16_t* wT2      = (uint16_t*)(ws + 7670784);  // 32 KB -> 7703552
    uint16_t* xb       = (uint16_t*)(ws + 7703552);  // 25.6 MB -> 33303552
    uint16_t* ab       = (uint16_t*)(ws + 33303552); // 25.6 MB -> 58903552
    uint16_t* hb       = (uint16_t*)(ws + 58903552); // 25.6 MB -> 84503552
    // aliases into hb (consumed before gemm1 writes hb; stream-ordered):
    uint32_t* packed   = (uint32_t*)hb;                 // 6.4 MB
    int*      hoff     = (int*)(ws + 58903552 + 6400000); // 611 KB hist/scan matrix
    // aliases (lifetimes disjoint):
    uint16_t* g        = xb;              // written by gemm2 after xb last read
    float*    z        = (float*)ab;      // written by gemm2 after ab last read

    // graph build (no global atomics)
    hist1_k<<<NBE, 256, 0, stream>>>(dstv, hoff);
    scan1_k<<<NB_SCAN, 256, 0, stream>>>(hoff, partials, HM);
    scan2_k<<<1, 256, 0, stream>>>(partials, NB_SCAN);
    scan3_k<<<(HM + 255) / 256, 256, 0, stream>>>(hoff, partials, HM);
    scatter2_k<<<NBE, 256, 0, stream>>>(srcv, dstv, hoff, packed);
    bucket_k<<<NBUCKET, 256, 0, stream>>>(packed, hoff, csr, deg, rowst);

    // dtype prep
    cast_x_k<<<12500, 256, 0, stream>>>(x, xb);
    prep_w_k<<<192, 256, 0, stream>>>(W1l, W1r, W2l, W2r, wT1, wT2);

    // layer 1: aggr(x) -> ab ; h = relu([ab|x] @ wT1^T + b1) -> hb
    aggregate_k<<<25000, 256, 0, stream>>>(csr, rowst, deg, (const uint32_t*)xb, (uint32_t*)ab);
    gemm1_k<<<1563, 256, 0, stream>>>(ab, xb, wT1, b1, hb);

    // layer 2: [g|z] = h @ [W2l|W2r] (+b2 on z) ; out = mean-aggr(g) + z
    gemm2_k<<<1563, 256, 0, stream>>>(hb, wT2, b2, g, z);
    agg2_k<<<25000, 256, 0, stream>>>(csr, rowst, deg, (const uint32_t*)g, z, out);
}

// Round 4
// 360.226 us; speedup vs baseline: 2.7667x; 1.1037x over previous
//
#include <hip/hip_runtime.h>
#include <hip/hip_bf16.h>
#include <stdint.h>

#define N_NODES 100000
#define N_EDGES 1600000
#define IN_DIM 128
#define HID_DIM 128
#define OUT_DIM 64
#define NBUCKET 391   // ceil(N_NODES/256), bucket = dst>>8
#define NBE 391       // edge blocks, 4096 edges each
#define ECHUNK 4096
#define HM (NBUCKET * NBE)          // 152881 hist entries
#define NB_SCAN 150                 // ceil(HM/1024)

typedef __bf16 bf16x8 __attribute__((ext_vector_type(8)));
typedef float f32x4 __attribute__((ext_vector_type(4)));

__device__ __forceinline__ float bf16lo_f(uint32_t p) {
    return __uint_as_float(p << 16);
}
__device__ __forceinline__ float bf16hi_f(uint32_t p) {
    return __uint_as_float(p & 0xffff0000u);
}
__device__ __forceinline__ uint16_t f_to_bf16(float f) {
    uint32_t u = __float_as_uint(f);
    u += 0x7fffu + ((u >> 16) & 1u);   // round-to-nearest-even
    return (uint16_t)(u >> 16);
}
__device__ __forceinline__ uint32_t pack_bf16x2(float lo, float hi) {
    return (uint32_t)f_to_bf16(lo) | ((uint32_t)f_to_bf16(hi) << 16);
}

// ---------------- graph build: atomic-free two-pass radix partition ----------------

__global__ __launch_bounds__(256) void hist1_k(const int* __restrict__ dst,
                                               int* __restrict__ hist) {
    __shared__ int lh[NBUCKET];
    int blk = blockIdx.x, t = threadIdx.x;
    for (int i = t; i < NBUCKET; i += 256) lh[i] = 0;
    __syncthreads();
    int e0 = blk * ECHUNK;
    int e1 = e0 + ECHUNK; if (e1 > N_EDGES) e1 = N_EDGES;
    for (int e = e0 + t; e < e1; e += 256) atomicAdd(&lh[dst[e] >> 8], 1);
    __syncthreads();
    for (int i = t; i < NBUCKET; i += 256) hist[i * NBE + blk] = lh[i];
}

__global__ void scan1_k(int* __restrict__ data, int* __restrict__ partials, int n) {
    __shared__ int sm[256];
    int tid = threadIdx.x;
    int base = blockIdx.x * 1024 + tid * 4;
    int v0 = 0, v1 = 0, v2 = 0, v3 = 0;
    if (base + 0 < n) v0 = data[base + 0];
    if (base + 1 < n) v1 = data[base + 1];
    if (base + 2 < n) v2 = data[base + 2];
    if (base + 3 < n) v3 = data[base + 3];
    int tot = v0 + v1 + v2 + v3;
    sm[tid] = tot;
    __syncthreads();
    int val = tot;
    for (int off = 1; off < 256; off <<= 1) {
        int x = (tid >= off) ? sm[tid - off] : 0;
        __syncthreads();
        val += x;
        sm[tid] = val;
        __syncthreads();
    }
    int excl = val - tot;
    if (tid == 255) partials[blockIdx.x] = val;
    if (base + 0 < n) data[base + 0] = excl;
    if (base + 1 < n) data[base + 1] = excl + v0;
    if (base + 2 < n) data[base + 2] = excl + v0 + v1;
    if (base + 3 < n) data[base + 3] = excl + v0 + v1 + v2;
}

__global__ void scan2_k(int* __restrict__ partials, int nb) {
    __shared__ int sm[256];
    int tid = threadIdx.x;
    int v = (tid < nb) ? partials[tid] : 0;
    sm[tid] = v;
    __syncthreads();
    int val = v;
    for (int off = 1; off < 256; off <<= 1) {
        int x = (tid >= off) ? sm[tid - off] : 0;
        __syncthreads();
        val += x;
        sm[tid] = val;
        __syncthreads();
    }
    if (tid < nb) partials[tid] = val - v;  // exclusive
}

__global__ void scan3_k(int* __restrict__ data, const int* __restrict__ partials, int n) {
    int i = blockIdx.x * blockDim.x + threadIdx.x;
    if (i < n) data[i] += partials[i >> 10];
}

__global__ __launch_bounds__(256) void scatter2_k(const int* __restrict__ src,
                                                  const int* __restrict__ dst,
                                                  const int* __restrict__ hoff,
                                                  uint32_t* __restrict__ packed) {
    __shared__ int loff[NBUCKET];
    int blk = blockIdx.x, t = threadIdx.x;
    for (int i = t; i < NBUCKET; i += 256) loff[i] = hoff[i * NBE + blk];
    __syncthreads();
    int e0 = blk * ECHUNK;
    int e1 = e0 + ECHUNK; if (e1 > N_EDGES) e1 = N_EDGES;
    for (int e = e0 + t; e < e1; e += 256) {
        int d = dst[e];
        int pos = atomicAdd(&loff[d >> 8], 1);
        packed[pos] = ((uint32_t)src[e] << 8) | (uint32_t)(d & 255);
    }
}

#define LCAP 6144
__global__ __launch_bounds__(256) void bucket_k(const uint32_t* __restrict__ packed,
                                                const int* __restrict__ hoff,
                                                int* __restrict__ csr,
                                                int* __restrict__ deg,
                                                int* __restrict__ rowst) {
    __shared__ int lhist[256];
    __shared__ int lcur[256];
    __shared__ int ssc[256];
    __shared__ uint32_t lpk[LCAP];
    __shared__ int lcsr[LCAP];
    int b = blockIdx.x, t = threadIdx.x;
    int base = hoff[b * NBE];
    int next = (b + 1 < NBUCKET) ? hoff[(b + 1) * NBE] : N_EDGES;
    int cnt = next - base;
    lhist[t] = 0;
    __syncthreads();
    bool fit = (cnt <= LCAP);
    if (fit) {
        for (int i = t; i < cnt; i += 256) {
            uint32_t pk = packed[base + i];
            lpk[i] = pk;
            atomicAdd(&lhist[pk & 255u], 1);
        }
    } else {
        for (int i = t; i < cnt; i += 256) {
            uint32_t pk = packed[base + i];
            atomicAdd(&lhist[pk & 255u], 1);
        }
    }
    __syncthreads();
    int cl = lhist[t];
    ssc[t] = cl;
    __syncthreads();
    int val = cl;
    for (int off = 1; off < 256; off <<= 1) {
        int x = (t >= off) ? ssc[t - off] : 0;
        __syncthreads();
        val += x;
        ssc[t] = val;
        __syncthreads();
    }
    int excl = val - cl;
    lcur[t] = excl;
    int node = (b << 8) + t;
    if (node < N_NODES) { deg[node] = cl; rowst[node] = base + excl; }
    __syncthreads();
    if (fit) {
        for (int i = t; i < cnt; i += 256) {
            uint32_t pk = lpk[i];
            int pos = atomicAdd(&lcur[pk & 255u], 1);
            lcsr[pos] = (int)(pk >> 8);
        }
        __syncthreads();
        for (int i = t; i < cnt; i += 256) csr[base + i] = lcsr[i];
    } else {
        for (int i = t; i < cnt; i += 256) {
            uint32_t pk = packed[base + i];
            int pos = atomicAdd(&lcur[pk & 255u], 1);
            csr[base + pos] = (int)(pk >> 8);
        }
    }
}

// ---------------- dtype prep ----------------

__global__ void cast_x_k(const float* __restrict__ x, uint16_t* __restrict__ xb) {
    int i = blockIdx.x * blockDim.x + threadIdx.x;
    if (i < N_NODES * IN_DIM / 4) {
        const float4* xv = (const float4*)x;
        float4 v = xv[i];
        union { uint16_t u[4]; uint64_t q; } o;
        o.u[0] = f_to_bf16(v.x);
        o.u[1] = f_to_bf16(v.y);
        o.u[2] = f_to_bf16(v.z);
        o.u[3] = f_to_bf16(v.w);
        ((uint64_t*)xb)[i] = o.q;
    }
}

__global__ void prep_w_k(const float* __restrict__ W1l, const float* __restrict__ W1r,
                         const float* __restrict__ W2l, const float* __restrict__ W2r,
                         uint16_t* __restrict__ wT1, uint16_t* __restrict__ wT2) {
    int i = blockIdx.x * blockDim.x + threadIdx.x;
    if (i < 128 * 256) {
        int n = i >> 8, k = i & 255;
        float v = (k < 128) ? W1l[k * 128 + n] : W1r[(k - 128) * 128 + n];
        wT1[i] = f_to_bf16(v);
    } else {
        int j = i - 128 * 256;
        if (j < 128 * 128) {
            int n = j >> 7, k = j & 127;
            float v = (n < 64) ? W2l[k * 64 + n] : W2r[k * 64 + (n - 64)];
            wT2[j] = f_to_bf16(v);
        }
    }
}

// ---------------- mean aggregation, 128-dim ----------------
// wave = 1 node. 32 lanes cover a row as uint2 (8B/lane); 2 rows per load,
// 8 load-slots per iteration => 16 rows (4KB) in flight.

__global__ void aggregate_k(const int* __restrict__ csr, const int* __restrict__ rowst,
                            const int* __restrict__ deg,
                            const uint2* __restrict__ in2, uint32_t* __restrict__ out2) {
    int gw = (blockIdx.x * blockDim.x + threadIdx.x) >> 6;
    int lane = threadIdx.x & 63;
    if (gw >= N_NODES) return;
    int start = rowst[gw];
    int d = deg[gw];
    int c = lane & 31, p = lane >> 5;
    float a0 = 0.f, a1 = 0.f, a2 = 0.f, a3 = 0.f;
    for (int j = 0; j < d; j += 16) {
        uint2 q[8];
#pragma unroll
        for (int u = 0; u < 8; u++) {
            int idx = j + 2 * u + p;
            q[u].x = 0u; q[u].y = 0u;
            if (idx < d) {
                int s = csr[start + idx];
                q[u] = in2[(size_t)s * 32 + c];
            }
        }
#pragma unroll
        for (int u = 0; u < 8; u++) {
            a0 += bf16lo_f(q[u].x); a1 += bf16hi_f(q[u].x);
            a2 += bf16lo_f(q[u].y); a3 += bf16hi_f(q[u].y);
        }
    }
    a0 += __shfl_xor(a0, 32, 64);
    a1 += __shfl_xor(a1, 32, 64);
    a2 += __shfl_xor(a2, 32, 64);
    a3 += __shfl_xor(a3, 32, 64);
    if (p == 0) {
        float inv = 1.0f / (float)(d > 0 ? d : 1);
        uint2 o;
        o.x = pack_bf16x2(a0 * inv, a1 * inv);
        o.y = pack_bf16x2(a2 * inv, a3 * inv);
        ((uint2*)out2)[(size_t)gw * 32 + c] = o;
    }
}

// ---------------- layer-1 GEMM: [aggr | x] (M x 256) @ wT1 (128 x 256)^T ----------------
// 2 row-stripes (32 rows) per wave: B fragments reused across stripes.
// mfma_f32_16x16x32_bf16: A lane m=lane&15, k=quad*8+j ; C/D: col=lane&15, row=quad*4+reg

__global__ __launch_bounds__(256) void gemm1_k(const uint16_t* __restrict__ ab,
                                               const uint16_t* __restrict__ xb,
                                               const uint16_t* __restrict__ wT1,
                                               const float* __restrict__ b1,
                                               uint16_t* __restrict__ hb) {
    int wave = (blockIdx.x * 256 + threadIdx.x) >> 6;
    int lane = threadIdx.x & 63;
    int m0 = wave * 32;
    if (m0 >= N_NODES) return;
    int mr = lane & 15, quad = lane >> 4;

    const uint16_t* A1s0 = ab + (size_t)(m0 + mr) * 128 + quad * 8;
    const uint16_t* A2s0 = xb + (size_t)(m0 + mr) * 128 + quad * 8;
    const uint16_t* A1s1 = A1s0 + 16 * 128;
    const uint16_t* A2s1 = A2s0 + 16 * 128;

    f32x4 acc[8][2];
#pragma unroll
    for (int nt = 0; nt < 8; nt++) {
        acc[nt][0] = (f32x4){0.f, 0.f, 0.f, 0.f};
        acc[nt][1] = (f32x4){0.f, 0.f, 0.f, 0.f};
    }

#pragma unroll
    for (int kt = 0; kt < 8; kt++) {
        const uint16_t* ap0 = (kt < 4) ? (A1s0 + kt * 32) : (A2s0 + (kt - 4) * 32);
        const uint16_t* ap1 = (kt < 4) ? (A1s1 + kt * 32) : (A2s1 + (kt - 4) * 32);
        bf16x8 a0 = *reinterpret_cast<const bf16x8*>(ap0);
        bf16x8 a1 = *reinterpret_cast<const bf16x8*>(ap1);
#pragma unroll
        for (int nt = 0; nt < 8; nt++) {
            const uint16_t* bp = wT1 + (size_t)(nt * 16 + mr) * 256 + kt * 32 + quad * 8;
            bf16x8 b = *reinterpret_cast<const bf16x8*>(bp);
            acc[nt][0] = __builtin_amdgcn_mfma_f32_16x16x32_bf16(a0, b, acc[nt][0], 0, 0, 0);
            acc[nt][1] = __builtin_amdgcn_mfma_f32_16x16x32_bf16(a1, b, acc[nt][1], 0, 0, 0);
        }
    }

#pragma unroll
    for (int nt = 0; nt < 8; nt++) {
        int col = nt * 16 + mr;
        float bias = b1[col];
#pragma unroll
        for (int s = 0; s < 2; s++) {
#pragma unroll
            for (int r = 0; r < 4; r++) {
                int row = m0 + s * 16 + quad * 4 + r;
                float v = acc[nt][s][r] + bias;
                v = v > 0.f ? v : 0.f;
                hb[(size_t)row * 128 + col] = f_to_bf16(v);
            }
        }
    }
}

// ---------------- layer-2 GEMM: h (M x 128) @ wT2 (128 x 128)^T ----------------
// cols 0..63 -> g = h@W2l (bf16); cols 64..127 -> z = h@W2r + b2 (fp32)

__global__ __launch_bounds__(256) void gemm2_k(const uint16_t* __restrict__ hb,
                                               const uint16_t* __restrict__ wT2,
                                               const float* __restrict__ b2,
                                               uint16_t* __restrict__ g,
                                               float* __restrict__ z) {
    int wave = (blockIdx.x * 256 + threadIdx.x) >> 6;
    int lane = threadIdx.x & 63;
    int m0 = wave * 32;
    if (m0 >= N_NODES) return;
    int mr = lane & 15, quad = lane >> 4;

    const uint16_t* As0 = hb + (size_t)(m0 + mr) * 128 + quad * 8;
    const uint16_t* As1 = As0 + 16 * 128;

    f32x4 acc[8][2];
#pragma unroll
    for (int nt = 0; nt < 8; nt++) {
        acc[nt][0] = (f32x4){0.f, 0.f, 0.f, 0.f};
        acc[nt][1] = (f32x4){0.f, 0.f, 0.f, 0.f};
    }

#pragma unroll
    for (int kt = 0; kt < 4; kt++) {
        bf16x8 a0 = *reinterpret_cast<const bf16x8*>(As0 + kt * 32);
        bf16x8 a1 = *reinterpret_cast<const bf16x8*>(As1 + kt * 32);
#pragma unroll
        for (int nt = 0; nt < 8; nt++) {
            const uint16_t* bp = wT2 + (size_t)(nt * 16 + mr) * 128 + kt * 32 + quad * 8;
            bf16x8 b = *reinterpret_cast<const bf16x8*>(bp);
            acc[nt][0] = __builtin_amdgcn_mfma_f32_16x16x32_bf16(a0, b, acc[nt][0], 0, 0, 0);
            acc[nt][1] = __builtin_amdgcn_mfma_f32_16x16x32_bf16(a1, b, acc[nt][1], 0, 0, 0);
        }
    }

#pragma unroll
    for (int nt = 0; nt < 8; nt++) {
        int col = nt * 16 + mr;
#pragma unroll
        for (int s = 0; s < 2; s++) {
#pragma unroll
            for (int r = 0; r < 4; r++) {
                int row = m0 + s * 16 + quad * 4 + r;
                if (nt < 4) {
                    g[(size_t)row * 64 + col] = f_to_bf16(acc[nt][s][r]);
                } else {
                    z[(size_t)row * 64 + (col - 64)] = acc[nt][s][r] + b2[col - 64];
                }
            }
        }
    }
}

// ---------------- layer-2 aggregation, 64-dim ----------------
// wave = 1 node. 16 lanes cover a row as uint2; 4 rows per load, 4 slots => 16 rows/iter.

__global__ void agg2_k(const int* __restrict__ csr, const int* __restrict__ rowst,
                       const int* __restrict__ deg,
                       const uint2* __restrict__ g2, const float* __restrict__ z,
                       float* __restrict__ out) {
    int w = (blockIdx.x * blockDim.x + threadIdx.x) >> 6;
    int lane = threadIdx.x & 63;
    if (w >= N_NODES) return;
    int start = rowst[w];
    int d = deg[w];
    int c = lane & 15, p = lane >> 4;
    float a0 = 0.f, a1 = 0.f, a2 = 0.f, a3 = 0.f;
    for (int j = 0; j < d; j += 16) {
        uint2 q[4];
#pragma unroll
        for (int u = 0; u < 4; u++) {
            int idx = j + 4 * u + p;
            q[u].x = 0u; q[u].y = 0u;
            if (idx < d) {
                int s = csr[start + idx];
                q[u] = g2[(size_t)s * 16 + c];
            }
        }
#pragma unroll
        for (int u = 0; u < 4; u++) {
            a0 += bf16lo_f(q[u].x); a1 += bf16hi_f(q[u].x);
            a2 += bf16lo_f(q[u].y); a3 += bf16hi_f(q[u].y);
        }
    }
    a0 += __shfl_xor(a0, 16, 64); a0 += __shfl_xor(a0, 32, 64);
    a1 += __shfl_xor(a1, 16, 64); a1 += __shfl_xor(a1, 32, 64);
    a2 += __shfl_xor(a2, 16, 64); a2 += __shfl_xor(a2, 32, 64);
    a3 += __shfl_xor(a3, 16, 64); a3 += __shfl_xor(a3, 32, 64);
    if (p == 0) {
        float inv = 1.0f / (float)(d > 0 ? d : 1);
        float4 zz = ((const float4*)z)[(size_t)w * 16 + c];
        float4 o;
        o.x = a0 * inv + zz.x;
        o.y = a1 * inv + zz.y;
        o.z = a2 * inv + zz.z;
        o.w = a3 * inv + zz.w;
        ((float4*)out)[(size_t)w * 16 + c] = o;
    }
}

// ---------------- launch ----------------

extern "C" void kernel_launch(void* const* d_in, const int* in_sizes, int n_in,
                              void* d_out, int out_size, void* d_ws, size_t ws_size,
                              hipStream_t stream) {
    const float* x   = (const float*)d_in[0];
    const int*  ei   = (const int*)d_in[1];
    const float* W1l = (const float*)d_in[2];
    const float* b1  = (const float*)d_in[3];
    const float* W1r = (const float*)d_in[4];
    const float* W2l = (const float*)d_in[5];
    const float* b2  = (const float*)d_in[6];
    const float* W2r = (const float*)d_in[7];
    float* out = (float*)d_out;

    const int* srcv = ei;            // edge_index[0]
    const int* dstv = ei + N_EDGES;  // edge_index[1]

    char* ws = (char*)d_ws;
    int*      deg      = (int*)(ws + 0);             // 100000 ints
    int*      rowst    = (int*)(ws + 401408);        // 100000 ints
    int*      partials = (int*)(ws + 802816);        // 150 ints
    int*      csr      = (int*)(ws + 1205248);       // 1.6M ints -> 7605248
    uint16_t* wT1      = (uint16_t*)(ws + 7605248);  // 64 KB -> 7670784
    uint16_t* wT2      = (uint16_t*)(ws + 7670784);  // 32 KB -> 7703552
    uint16_t* xb       = (uint16_t*)(ws + 7703552);  // 25.6 MB -> 33303552
    uint16_t* ab       = (uint16_t*)(ws + 33303552); // 25.6 MB -> 58903552
    uint16_t* hb       = (uint16_t*)(ws + 58903552); // 25.6 MB -> 84503552
    // aliases into hb (consumed before gemm1 writes hb; stream-ordered):
    uint32_t* packed   = (uint32_t*)hb;                 // 6.4 MB
    int*      hoff     = (int*)(ws + 58903552 + 6400000); // 611 KB hist/scan matrix
    // aliases (lifetimes disjoint):
    uint16_t* g        = xb;              // written by gemm2 after xb last read
    float*    z        = (float*)ab;      // written by gemm2 after ab last read

    // graph build (no global atomics)
    hist1_k<<<NBE, 256, 0, stream>>>(dstv, hoff);
    scan1_k<<<NB_SCAN, 256, 0, stream>>>(hoff, partials, HM);
    scan2_k<<<1, 256, 0, stream>>>(partials, NB_SCAN);
    scan3_k<<<(HM + 255) / 256, 256, 0, stream>>>(hoff, partials, HM);
    scatter2_k<<<NBE, 256, 0, stream>>>(srcv, dstv, hoff, packed);
    bucket_k<<<NBUCKET, 256, 0, stream>>>(packed, hoff, csr, deg, rowst);

    // dtype prep
    cast_x_k<<<12500, 256, 0, stream>>>(x, xb);
    prep_w_k<<<192, 256, 0, stream>>>(W1l, W1r, W2l, W2r, wT1, wT2);

    // layer 1: aggr(x) -> ab ; h = relu([ab|x] @ wT1^T + b1) -> hb
    aggregate_k<<<25000, 256, 0, stream>>>(csr, rowst, deg, (const uint2*)xb, (uint32_t*)ab);
    gemm1_k<<<782, 256, 0, stream>>>(ab, xb, wT1, b1, hb);

    // layer 2: [g|z] = h @ [W2l|W2r] (+b2 on z) ; out = mean-aggr(g) + z
    gemm2_k<<<782, 256, 0, stream>>>(hb, wT2, b2, g, z);
    agg2_k<<<25000, 256, 0, stream>>>(csr, rowst, deg, (const uint2*)g, z, out);
}

// Round 5
// 349.826 us; speedup vs baseline: 2.8490x; 1.0297x over previous
//
#include <hip/hip_runtime.h>
#include <hip/hip_bf16.h>
#include <stdint.h>

#define N_NODES 100000
#define N_EDGES 1600000
#define IN_DIM 128
#define HID_DIM 128
#define OUT_DIM 64
#define NBUCKET 391   // ceil(N_NODES/256), bucket = dst>>8
#define NBE 391       // edge blocks, 4096 edges each
#define ECHUNK 4096
#define HM (NBUCKET * NBE)          // 152881 hist entries
#define NB_SCAN 150                 // ceil(HM/1024)

typedef __bf16 bf16x8 __attribute__((ext_vector_type(8)));
typedef float f32x4 __attribute__((ext_vector_type(4)));
typedef float f32x2 __attribute__((ext_vector_type(2)));

__device__ __forceinline__ uint16_t f_to_bf16(float f) {
    uint32_t u = __float_as_uint(f);
    u += 0x7fffu + ((u >> 16) & 1u);   // round-to-nearest-even
    return (uint16_t)(u >> 16);
}
__device__ __forceinline__ uint32_t pack_bf16x2(float lo, float hi) {
    return (uint32_t)f_to_bf16(lo) | ((uint32_t)f_to_bf16(hi) << 16);
}

// ---------------- graph build: atomic-free two-pass radix partition ----------------

__global__ __launch_bounds__(256) void hist1_k(const int* __restrict__ dst,
                                               int* __restrict__ hist) {
    __shared__ int lh[NBUCKET];
    int blk = blockIdx.x, t = threadIdx.x;
    for (int i = t; i < NBUCKET; i += 256) lh[i] = 0;
    __syncthreads();
    int e0 = blk * ECHUNK;
    int e1 = e0 + ECHUNK; if (e1 > N_EDGES) e1 = N_EDGES;
    for (int e = e0 + t; e < e1; e += 256) atomicAdd(&lh[dst[e] >> 8], 1);
    __syncthreads();
    for (int i = t; i < NBUCKET; i += 256) hist[i * NBE + blk] = lh[i];
}

__global__ void scan1_k(int* __restrict__ data, int* __restrict__ partials, int n) {
    __shared__ int sm[256];
    int tid = threadIdx.x;
    int base = blockIdx.x * 1024 + tid * 4;
    int v0 = 0, v1 = 0, v2 = 0, v3 = 0;
    if (base + 0 < n) v0 = data[base + 0];
    if (base + 1 < n) v1 = data[base + 1];
    if (base + 2 < n) v2 = data[base + 2];
    if (base + 3 < n) v3 = data[base + 3];
    int tot = v0 + v1 + v2 + v3;
    sm[tid] = tot;
    __syncthreads();
    int val = tot;
    for (int off = 1; off < 256; off <<= 1) {
        int x = (tid >= off) ? sm[tid - off] : 0;
        __syncthreads();
        val += x;
        sm[tid] = val;
        __syncthreads();
    }
    int excl = val - tot;
    if (tid == 255) partials[blockIdx.x] = val;
    if (base + 0 < n) data[base + 0] = excl;
    if (base + 1 < n) data[base + 1] = excl + v0;
    if (base + 2 < n) data[base + 2] = excl + v0 + v1;
    if (base + 3 < n) data[base + 3] = excl + v0 + v1 + v2;
}

__global__ void scan2_k(int* __restrict__ partials, int nb) {
    __shared__ int sm[256];
    int tid = threadIdx.x;
    int v = (tid < nb) ? partials[tid] : 0;
    sm[tid] = v;
    __syncthreads();
    int val = v;
    for (int off = 1; off < 256; off <<= 1) {
        int x = (tid >= off) ? sm[tid - off] : 0;
        __syncthreads();
        val += x;
        sm[tid] = val;
        __syncthreads();
    }
    if (tid < nb) partials[tid] = val - v;  // exclusive
}

__global__ void scan3_k(int* __restrict__ data, const int* __restrict__ partials, int n) {
    int i = blockIdx.x * blockDim.x + threadIdx.x;
    if (i < n) data[i] += partials[i >> 10];
}

__global__ __launch_bounds__(256) void scatter2_k(const int* __restrict__ src,
                                                  const int* __restrict__ dst,
                                                  const int* __restrict__ hoff,
                                                  uint32_t* __restrict__ packed) {
    __shared__ int loff[NBUCKET];
    int blk = blockIdx.x, t = threadIdx.x;
    for (int i = t; i < NBUCKET; i += 256) loff[i] = hoff[i * NBE + blk];
    __syncthreads();
    int e0 = blk * ECHUNK;
    int e1 = e0 + ECHUNK; if (e1 > N_EDGES) e1 = N_EDGES;
    for (int e = e0 + t; e < e1; e += 256) {
        int d = dst[e];
        int pos = atomicAdd(&loff[d >> 8], 1);
        packed[pos] = ((uint32_t)src[e] << 8) | (uint32_t)(d & 255);
    }
}

#define LCAP 6144
__global__ __launch_bounds__(256) void bucket_k(const uint32_t* __restrict__ packed,
                                                const int* __restrict__ hoff,
                                                int* __restrict__ csr,
                                                int* __restrict__ deg,
                                                int* __restrict__ rowst) {
    __shared__ int lhist[256];
    __shared__ int lcur[256];
    __shared__ int ssc[256];
    __shared__ uint32_t lpk[LCAP];
    __shared__ int lcsr[LCAP];
    int b = blockIdx.x, t = threadIdx.x;
    int base = hoff[b * NBE];
    int next = (b + 1 < NBUCKET) ? hoff[(b + 1) * NBE] : N_EDGES;
    int cnt = next - base;
    lhist[t] = 0;
    __syncthreads();
    bool fit = (cnt <= LCAP);
    if (fit) {
        for (int i = t; i < cnt; i += 256) {
            uint32_t pk = packed[base + i];
            lpk[i] = pk;
            atomicAdd(&lhist[pk & 255u], 1);
        }
    } else {
        for (int i = t; i < cnt; i += 256) {
            uint32_t pk = packed[base + i];
            atomicAdd(&lhist[pk & 255u], 1);
        }
    }
    __syncthreads();
    int cl = lhist[t];
    ssc[t] = cl;
    __syncthreads();
    int val = cl;
    for (int off = 1; off < 256; off <<= 1) {
        int x = (t >= off) ? ssc[t - off] : 0;
        __syncthreads();
        val += x;
        ssc[t] = val;
        __syncthreads();
    }
    int excl = val - cl;
    lcur[t] = excl;
    int node = (b << 8) + t;
    if (node < N_NODES) { deg[node] = cl; rowst[node] = base + excl; }
    __syncthreads();
    if (fit) {
        for (int i = t; i < cnt; i += 256) {
            uint32_t pk = lpk[i];
            int pos = atomicAdd(&lcur[pk & 255u], 1);
            lcsr[pos] = (int)(pk >> 8);
        }
        __syncthreads();
        for (int i = t; i < cnt; i += 256) csr[base + i] = lcsr[i];
    } else {
        for (int i = t; i < cnt; i += 256) {
            uint32_t pk = packed[base + i];
            int pos = atomicAdd(&lcur[pk & 255u], 1);
            csr[base + pos] = (int)(pk >> 8);
        }
    }
}

// ---------------- dtype prep: x -> bf16 copy (GEMM) + fp8 copy (gather) ----------------

__global__ void cast_x_k(const float* __restrict__ x, uint16_t* __restrict__ xb,
                         uint32_t* __restrict__ xf8) {
    int i = blockIdx.x * blockDim.x + threadIdx.x;   // 8 floats per thread
    if (i >= N_NODES * IN_DIM / 8) return;
    const float4* xv = (const float4*)x;
    float4 v0 = xv[2 * i], v1 = xv[2 * i + 1];
    union { uint16_t u[8]; uint4 q; } o;
    o.u[0] = f_to_bf16(v0.x); o.u[1] = f_to_bf16(v0.y);
    o.u[2] = f_to_bf16(v0.z); o.u[3] = f_to_bf16(v0.w);
    o.u[4] = f_to_bf16(v1.x); o.u[5] = f_to_bf16(v1.y);
    o.u[6] = f_to_bf16(v1.z); o.u[7] = f_to_bf16(v1.w);
    ((uint4*)xb)[i] = o.q;
    int p0 = __builtin_amdgcn_cvt_pk_fp8_f32(v0.x, v0.y, 0, false);
    p0 = __builtin_amdgcn_cvt_pk_fp8_f32(v0.z, v0.w, p0, true);
    int p1 = __builtin_amdgcn_cvt_pk_fp8_f32(v1.x, v1.y, 0, false);
    p1 = __builtin_amdgcn_cvt_pk_fp8_f32(v1.z, v1.w, p1, true);
    uint2 w2; w2.x = (uint32_t)p0; w2.y = (uint32_t)p1;
    ((uint2*)xf8)[i] = w2;
}

__global__ void prep_w_k(const float* __restrict__ W1l, const float* __restrict__ W1r,
                         const float* __restrict__ W2l, const float* __restrict__ W2r,
                         uint16_t* __restrict__ wT1, uint16_t* __restrict__ wT2) {
    int i = blockIdx.x * blockDim.x + threadIdx.x;
    if (i < 128 * 256) {
        int n = i >> 8, k = i & 255;
        float v = (k < 128) ? W1l[k * 128 + n] : W1r[(k - 128) * 128 + n];
        wT1[i] = f_to_bf16(v);
    } else {
        int j = i - 128 * 256;
        if (j < 128 * 128) {
            int n = j >> 7, k = j & 127;
            float v = (n < 64) ? W2l[k * 64 + n] : W2r[k * 64 + (n - 64)];
            wT2[j] = f_to_bf16(v);
        }
    }
}

// ---------------- layer-1 mean aggregation, fp8 gather (128 B rows) ----------------
// wave = 1 node. 32 lanes cover a row as uint32 (4 fp8/lane); 2 rows per slot,
// 8 slots => 16 rows (2KB) in flight. fp32 accumulate, bf16 out.

__global__ void aggregate_k(const int* __restrict__ csr, const int* __restrict__ rowst,
                            const int* __restrict__ deg,
                            const uint32_t* __restrict__ inf8, uint32_t* __restrict__ out2) {
    int gw = (blockIdx.x * blockDim.x + threadIdx.x) >> 6;
    int lane = threadIdx.x & 63;
    if (gw >= N_NODES) return;
    int start = rowst[gw];
    int d = deg[gw];
    int c = lane & 31, p = lane >> 5;
    float a0 = 0.f, a1 = 0.f, a2 = 0.f, a3 = 0.f;
    for (int j = 0; j < d; j += 16) {
        uint32_t q[8];
#pragma unroll
        for (int u = 0; u < 8; u++) {
            int idx = j + 2 * u + p;
            q[u] = 0u;                       // fp8 0x00 decodes to 0.0
            if (idx < d) {
                int s = csr[start + idx];
                q[u] = inf8[(size_t)s * 32 + c];
            }
        }
#pragma unroll
        for (int u = 0; u < 8; u++) {
            f32x2 lo = __builtin_amdgcn_cvt_pk_f32_fp8((int)q[u], false);
            f32x2 hi = __builtin_amdgcn_cvt_pk_f32_fp8((int)q[u], true);
            a0 += lo[0]; a1 += lo[1]; a2 += hi[0]; a3 += hi[1];
        }
    }
    a0 += __shfl_xor(a0, 32, 64);
    a1 += __shfl_xor(a1, 32, 64);
    a2 += __shfl_xor(a2, 32, 64);
    a3 += __shfl_xor(a3, 32, 64);
    if (p == 0) {
        float inv = 1.0f / (float)(d > 0 ? d : 1);
        uint2 o;
        o.x = pack_bf16x2(a0 * inv, a1 * inv);
        o.y = pack_bf16x2(a2 * inv, a3 * inv);
        ((uint2*)out2)[(size_t)gw * 32 + c] = o;
    }
}

// ---------------- layer-1 GEMM: [aggr | x] (M x 256) @ wT1 (128 x 256)^T ----------------
// 2 row-stripes (32 rows) per wave; B fragments reused across stripes.
// mfma_f32_16x16x32_bf16: A lane m=lane&15, k=quad*8+j ; C/D: col=lane&15, row=quad*4+reg

__global__ __launch_bounds__(256) void gemm1_k(const uint16_t* __restrict__ ab,
                                               const uint16_t* __restrict__ xb,
                                               const uint16_t* __restrict__ wT1,
                                               const float* __restrict__ b1,
                                               uint16_t* __restrict__ hb) {
    int wave = (blockIdx.x * 256 + threadIdx.x) >> 6;
    int lane = threadIdx.x & 63;
    int m0 = wave * 32;
    if (m0 >= N_NODES) return;
    int mr = lane & 15, quad = lane >> 4;

    const uint16_t* A1s0 = ab + (size_t)(m0 + mr) * 128 + quad * 8;
    const uint16_t* A2s0 = xb + (size_t)(m0 + mr) * 128 + quad * 8;
    const uint16_t* A1s1 = A1s0 + 16 * 128;
    const uint16_t* A2s1 = A2s0 + 16 * 128;

    f32x4 acc[8][2];
#pragma unroll
    for (int nt = 0; nt < 8; nt++) {
        acc[nt][0] = (f32x4){0.f, 0.f, 0.f, 0.f};
        acc[nt][1] = (f32x4){0.f, 0.f, 0.f, 0.f};
    }

#pragma unroll
    for (int kt = 0; kt < 8; kt++) {
        const uint16_t* ap0 = (kt < 4) ? (A1s0 + kt * 32) : (A2s0 + (kt - 4) * 32);
        const uint16_t* ap1 = (kt < 4) ? (A1s1 + kt * 32) : (A2s1 + (kt - 4) * 32);
        bf16x8 a0 = *reinterpret_cast<const bf16x8*>(ap0);
        bf16x8 a1 = *reinterpret_cast<const bf16x8*>(ap1);
#pragma unroll
        for (int nt = 0; nt < 8; nt++) {
            const uint16_t* bp = wT1 + (size_t)(nt * 16 + mr) * 256 + kt * 32 + quad * 8;
            bf16x8 b = *reinterpret_cast<const bf16x8*>(bp);
            acc[nt][0] = __builtin_amdgcn_mfma_f32_16x16x32_bf16(a0, b, acc[nt][0], 0, 0, 0);
            acc[nt][1] = __builtin_amdgcn_mfma_f32_16x16x32_bf16(a1, b, acc[nt][1], 0, 0, 0);
        }
    }

#pragma unroll
    for (int nt = 0; nt < 8; nt++) {
        int col = nt * 16 + mr;
        float bias = b1[col];
#pragma unroll
        for (int s = 0; s < 2; s++) {
#pragma unroll
            for (int r = 0; r < 4; r++) {
                int row = m0 + s * 16 + quad * 4 + r;
                float v = acc[nt][s][r] + bias;
                v = v > 0.f ? v : 0.f;
                hb[(size_t)row * 128 + col] = f_to_bf16(v);
            }
        }
    }
}

// ---------------- layer-2 GEMM: h (M x 128) @ wT2 (128 x 128)^T ----------------
// cols 0..63 -> g = h@W2l (fp8, gathered by agg2); cols 64..127 -> z = h@W2r + b2 (fp32)

__global__ __launch_bounds__(256) void gemm2_k(const uint16_t* __restrict__ hb,
                                               const uint16_t* __restrict__ wT2,
                                               const float* __restrict__ b2,
                                               uint8_t* __restrict__ g,
                                               float* __restrict__ z) {
    int wave = (blockIdx.x * 256 + threadIdx.x) >> 6;
    int lane = threadIdx.x & 63;
    int m0 = wave * 32;
    if (m0 >= N_NODES) return;
    int mr = lane & 15, quad = lane >> 4;

    const uint16_t* As0 = hb + (size_t)(m0 + mr) * 128 + quad * 8;
    const uint16_t* As1 = As0 + 16 * 128;

    f32x4 acc[8][2];
#pragma unroll
    for (int nt = 0; nt < 8; nt++) {
        acc[nt][0] = (f32x4){0.f, 0.f, 0.f, 0.f};
        acc[nt][1] = (f32x4){0.f, 0.f, 0.f, 0.f};
    }

#pragma unroll
    for (int kt = 0; kt < 4; kt++) {
        bf16x8 a0 = *reinterpret_cast<const bf16x8*>(As0 + kt * 32);
        bf16x8 a1 = *reinterpret_cast<const bf16x8*>(As1 + kt * 32);
#pragma unroll
        for (int nt = 0; nt < 8; nt++) {
            const uint16_t* bp = wT2 + (size_t)(nt * 16 + mr) * 128 + kt * 32 + quad * 8;
            bf16x8 b = *reinterpret_cast<const bf16x8*>(bp);
            acc[nt][0] = __builtin_amdgcn_mfma_f32_16x16x32_bf16(a0, b, acc[nt][0], 0, 0, 0);
            acc[nt][1] = __builtin_amdgcn_mfma_f32_16x16x32_bf16(a1, b, acc[nt][1], 0, 0, 0);
        }
    }

#pragma unroll
    for (int nt = 0; nt < 8; nt++) {
        int col = nt * 16 + mr;
#pragma unroll
        for (int s = 0; s < 2; s++) {
#pragma unroll
            for (int r = 0; r < 4; r++) {
                int row = m0 + s * 16 + quad * 4 + r;
                if (nt < 4) {
                    float v = acc[nt][s][r];
                    int pk = __builtin_amdgcn_cvt_pk_fp8_f32(v, v, 0, false);
                    g[(size_t)row * 64 + col] = (uint8_t)(pk & 0xff);
                } else {
                    z[(size_t)row * 64 + (col - 64)] = acc[nt][s][r] + b2[col - 64];
                }
            }
        }
    }
}

// ---------------- layer-2 aggregation, fp8 gather (64 B rows) ----------------
// wave = 1 node. 16 lanes cover a row as uint32 (4 fp8/lane); 4 rows per slot,
// 4 slots => 16 rows/iter.

__global__ void agg2_k(const int* __restrict__ csr, const int* __restrict__ rowst,
                       const int* __restrict__ deg,
                       const uint32_t* __restrict__ g4, const float* __restrict__ z,
                       float* __restrict__ out) {
    int w = (blockIdx.x * blockDim.x + threadIdx.x) >> 6;
    int lane = threadIdx.x & 63;
    if (w >= N_NODES) return;
    int start = rowst[w];
    int d = deg[w];
    int c = lane & 15, p = lane >> 4;
    float a0 = 0.f, a1 = 0.f, a2 = 0.f, a3 = 0.f;
    for (int j = 0; j < d; j += 16) {
        uint32_t q[4];
#pragma unroll
        for (int u = 0; u < 4; u++) {
            int idx = j + 4 * u + p;
            q[u] = 0u;
            if (idx < d) {
                int s = csr[start + idx];
                q[u] = g4[(size_t)s * 16 + c];
            }
        }
#pragma unroll
        for (int u = 0; u < 4; u++) {
            f32x2 lo = __builtin_amdgcn_cvt_pk_f32_fp8((int)q[u], false);
            f32x2 hi = __builtin_amdgcn_cvt_pk_f32_fp8((int)q[u], true);
            a0 += lo[0]; a1 += lo[1]; a2 += hi[0]; a3 += hi[1];
        }
    }
    a0 += __shfl_xor(a0, 16, 64); a0 += __shfl_xor(a0, 32, 64);
    a1 += __shfl_xor(a1, 16, 64); a1 += __shfl_xor(a1, 32, 64);
    a2 += __shfl_xor(a2, 16, 64); a2 += __shfl_xor(a2, 32, 64);
    a3 += __shfl_xor(a3, 16, 64); a3 += __shfl_xor(a3, 32, 64);
    if (p == 0) {
        float inv = 1.0f / (float)(d > 0 ? d : 1);
        float4 zz = ((const float4*)z)[(size_t)w * 16 + c];
        float4 o;
        o.x = a0 * inv + zz.x;
        o.y = a1 * inv + zz.y;
        o.z = a2 * inv + zz.z;
        o.w = a3 * inv + zz.w;
        ((float4*)out)[(size_t)w * 16 + c] = o;
    }
}

// ---------------- launch ----------------

extern "C" void kernel_launch(void* const* d_in, const int* in_sizes, int n_in,
                              void* d_out, int out_size, void* d_ws, size_t ws_size,
                              hipStream_t stream) {
    const float* x   = (const float*)d_in[0];
    const int*  ei   = (const int*)d_in[1];
    const float* W1l = (const float*)d_in[2];
    const float* b1  = (const float*)d_in[3];
    const float* W1r = (const float*)d_in[4];
    const float* W2l = (const float*)d_in[5];
    const float* b2  = (const float*)d_in[6];
    const float* W2r = (const float*)d_in[7];
    float* out = (float*)d_out;

    const int* srcv = ei;            // edge_index[0]
    const int* dstv = ei + N_EDGES;  // edge_index[1]

    char* ws = (char*)d_ws;
    int*      deg      = (int*)(ws + 0);             // 100000 ints
    int*      rowst    = (int*)(ws + 401408);        // 100000 ints
    int*      partials = (int*)(ws + 802816);        // 150 ints
    int*      csr      = (int*)(ws + 1205248);       // 1.6M ints -> 7605248
    uint16_t* wT1      = (uint16_t*)(ws + 7605248);  // 64 KB -> 7670784
    uint16_t* wT2      = (uint16_t*)(ws + 7670784);  // 32 KB -> 7703552
    uint16_t* xb       = (uint16_t*)(ws + 7703552);  // 25.6 MB -> 33303552
    uint16_t* ab       = (uint16_t*)(ws + 33303552); // 25.6 MB -> 58903552
    uint16_t* hb       = (uint16_t*)(ws + 58903552); // 25.6 MB -> 84503552
    // aliases into hb region (all consumed before gemm1 writes hb; stream-ordered):
    uint32_t* packed   = (uint32_t*)hb;                   // +0       .. 6.40 MB
    int*      hoff     = (int*)(ws + 58903552 + 6400000); // +6.40 MB .. 7.01 MB
    uint32_t* xf8      = (uint32_t*)(ws + 58903552 + 7013376); // +7.01 .. 19.8 MB (12.8 MB)
    // aliases (lifetimes disjoint):
    uint8_t*  g        = (uint8_t*)xb;    // 6.4 MB fp8; written by gemm2 after xb last read
    float*    z        = (float*)ab;      // 25.6 MB;    written by gemm2 after ab last read

    // graph build (no global atomics)
    hist1_k<<<NBE, 256, 0, stream>>>(dstv, hoff);
    scan1_k<<<NB_SCAN, 256, 0, stream>>>(hoff, partials, HM);
    scan2_k<<<1, 256, 0, stream>>>(partials, NB_SCAN);
    scan3_k<<<(HM + 255) / 256, 256, 0, stream>>>(hoff, partials, HM);
    scatter2_k<<<NBE, 256, 0, stream>>>(srcv, dstv, hoff, packed);
    bucket_k<<<NBUCKET, 256, 0, stream>>>(packed, hoff, csr, deg, rowst);

    // dtype prep (xf8 disjoint from packed/hoff; hb overwritten only by gemm1 later)
    cast_x_k<<<6250, 256, 0, stream>>>(x, xb, xf8);
    prep_w_k<<<192, 256, 0, stream>>>(W1l, W1r, W2l, W2r, wT1, wT2);

    // layer 1: aggr(x_fp8) -> ab(bf16) ; h = relu([ab|x] @ wT1^T + b1) -> hb
    aggregate_k<<<25000, 256, 0, stream>>>(csr, rowst, deg, xf8, (uint32_t*)ab);
    gemm1_k<<<782, 256, 0, stream>>>(ab, xb, wT1, b1, hb);

    // layer 2: [g|z] = h @ [W2l|W2r] (+b2 on z), g in fp8 ; out = mean-aggr(g) + z
    gemm2_k<<<782, 256, 0, stream>>>(hb, wT2, b2, g, z);
    agg2_k<<<25000, 256, 0, stream>>>(csr, rowst, deg, (const uint32_t*)g, z, out);
}

// Round 6
// 310.844 us; speedup vs baseline: 3.2062x; 1.1254x over previous
//
#include <hip/hip_runtime.h>
#include <hip/hip_bf16.h>
#include <stdint.h>

#define N_NODES 100000
#define N_EDGES 1600000
#define IN_DIM 128
#define HID_DIM 128
#define OUT_DIM 64
#define NBUCKET 391   // ceil(N_NODES/256), bucket = dst>>8
#define NBE 391       // edge blocks, 4096 edges each
#define ECHUNK 4096
#define HM (NBUCKET * NBE)          // 152881 hist entries
#define NB_SCAN 150                 // ceil(HM/1024)
#define SENTINEL N_NODES            // padded-slot src -> zero row

typedef __bf16 bf16x8 __attribute__((ext_vector_type(8)));
typedef float f32x4 __attribute__((ext_vector_type(4)));
typedef float f32x2 __attribute__((ext_vector_type(2)));

__device__ __forceinline__ float bf16lo_f(uint32_t p) {
    return __uint_as_float(p << 16);
}
__device__ __forceinline__ float bf16hi_f(uint32_t p) {
    return __uint_as_float(p & 0xffff0000u);
}
__device__ __forceinline__ uint16_t f_to_bf16(float f) {
    uint32_t u = __float_as_uint(f);
    u += 0x7fffu + ((u >> 16) & 1u);   // round-to-nearest-even
    return (uint16_t)(u >> 16);
}
__device__ __forceinline__ uint32_t pack_bf16x2(float lo, float hi) {
    return (uint32_t)f_to_bf16(lo) | ((uint32_t)f_to_bf16(hi) << 16);
}

// ---------------- graph build: atomic-free two-pass radix partition ----------------

__global__ __launch_bounds__(256) void hist1_k(const int* __restrict__ dst,
                                               int* __restrict__ hist) {
    __shared__ int lh[NBUCKET];
    int blk = blockIdx.x, t = threadIdx.x;
    for (int i = t; i < NBUCKET; i += 256) lh[i] = 0;
    __syncthreads();
    int e0 = blk * ECHUNK;
    int e1 = e0 + ECHUNK; if (e1 > N_EDGES) e1 = N_EDGES;
    for (int e = e0 + t; e < e1; e += 256) atomicAdd(&lh[dst[e] >> 8], 1);
    __syncthreads();
    for (int i = t; i < NBUCKET; i += 256) hist[i * NBE + blk] = lh[i];
}

__global__ void scan1_k(int* __restrict__ data, int* __restrict__ partials, int n) {
    __shared__ int sm[256];
    int tid = threadIdx.x;
    int base = blockIdx.x * 1024 + tid * 4;
    int v0 = 0, v1 = 0, v2 = 0, v3 = 0;
    if (base + 0 < n) v0 = data[base + 0];
    if (base + 1 < n) v1 = data[base + 1];
    if (base + 2 < n) v2 = data[base + 2];
    if (base + 3 < n) v3 = data[base + 3];
    int tot = v0 + v1 + v2 + v3;
    sm[tid] = tot;
    __syncthreads();
    int val = tot;
    for (int off = 1; off < 256; off <<= 1) {
        int x = (tid >= off) ? sm[tid - off] : 0;
        __syncthreads();
        val += x;
        sm[tid] = val;
        __syncthreads();
    }
    int excl = val - tot;
    if (tid == 255) partials[blockIdx.x] = val;
    if (base + 0 < n) data[base + 0] = excl;
    if (base + 1 < n) data[base + 1] = excl + v0;
    if (base + 2 < n) data[base + 2] = excl + v0 + v1;
    if (base + 3 < n) data[base + 3] = excl + v0 + v1 + v2;
}

__global__ void scan2_k(int* __restrict__ partials, int nb) {
    __shared__ int sm[256];
    int tid = threadIdx.x;
    int v = (tid < nb) ? partials[tid] : 0;
    sm[tid] = v;
    __syncthreads();
    int val = v;
    for (int off = 1; off < 256; off <<= 1) {
        int x = (tid >= off) ? sm[tid - off] : 0;
        __syncthreads();
        val += x;
        sm[tid] = val;
        __syncthreads();
    }
    if (tid < nb) partials[tid] = val - v;  // exclusive
}

__global__ void scan3_k(int* __restrict__ data, const int* __restrict__ partials, int n) {
    int i = blockIdx.x * blockDim.x + threadIdx.x;
    if (i < n) data[i] += partials[i >> 10];
}

__global__ __launch_bounds__(256) void scatter2_k(const int* __restrict__ src,
                                                  const int* __restrict__ dst,
                                                  const int* __restrict__ hoff,
                                                  uint32_t* __restrict__ packed) {
    __shared__ int loff[NBUCKET];
    int blk = blockIdx.x, t = threadIdx.x;
    for (int i = t; i < NBUCKET; i += 256) loff[i] = hoff[i * NBE + blk];
    __syncthreads();
    int e0 = blk * ECHUNK;
    int e1 = e0 + ECHUNK; if (e1 > N_EDGES) e1 = N_EDGES;
    for (int e = e0 + t; e < e1; e += 256) {
        int d = dst[e];
        int pos = atomicAdd(&loff[d >> 8], 1);
        packed[pos] = ((uint32_t)src[e] << 8) | (uint32_t)(d & 255);
    }
}

// per-bucket node histogram -> deg, per-node padded excl scan -> ppos, bucket padded total
__global__ __launch_bounds__(256) void bhist_k(const uint32_t* __restrict__ packed,
                                               const int* __restrict__ hoff,
                                               int* __restrict__ deg,
                                               int* __restrict__ ppos,
                                               int* __restrict__ pbtot) {
    __shared__ int lhist[256];
    __shared__ int ssc[256];
    int b = blockIdx.x, t = threadIdx.x;
    int base = hoff[b * NBE];
    int next = (b + 1 < NBUCKET) ? hoff[(b + 1) * NBE] : N_EDGES;
    int cnt = next - base;
    lhist[t] = 0;
    __syncthreads();
    for (int i = t; i < cnt; i += 256) atomicAdd(&lhist[packed[base + i] & 255u], 1);
    __syncthreads();
    int d = lhist[t];
    int pd = (d + 15) & ~15;
    ssc[t] = pd;
    __syncthreads();
    int val = pd;
    for (int off = 1; off < 256; off <<= 1) {
        int x = (t >= off) ? ssc[t - off] : 0;
        __syncthreads();
        val += x;
        ssc[t] = val;
        __syncthreads();
    }
    int node = (b << 8) + t;
    if (node < N_NODES) { deg[node] = d; ppos[node] = val - pd; }
    if (t == 255) pbtot[b] = val;
}

// exclusive scan of 391 padded bucket totals
__global__ void pscan_k(const int* __restrict__ pbtot, int* __restrict__ pbase) {
    __shared__ int sm[512];
    int t = threadIdx.x;
    int v = (t < NBUCKET) ? pbtot[t] : 0;
    sm[t] = v;
    __syncthreads();
    int val = v;
    for (int off = 1; off < 512; off <<= 1) {
        int x = (t >= off) ? sm[t - off] : 0;
        __syncthreads();
        val += x;
        sm[t] = val;
        __syncthreads();
    }
    if (t < NBUCKET) pbase[t] = val - v;
}

// padded CSR scatter: sentinel-filled pads, per-node padded row starts
#define LCAP2 8192
__global__ __launch_bounds__(256) void pscatter_k(const uint32_t* __restrict__ packed,
                                                  const int* __restrict__ hoff,
                                                  const int* __restrict__ ppos,
                                                  const int* __restrict__ pbtot,
                                                  const int* __restrict__ pbase,
                                                  int* __restrict__ csr,
                                                  int* __restrict__ prowst) {
    __shared__ int lcur[256];
    __shared__ int lcsr[LCAP2];
    int b = blockIdx.x, t = threadIdx.x;
    int base = hoff[b * NBE];
    int next = (b + 1 < NBUCKET) ? hoff[(b + 1) * NBE] : N_EDGES;
    int cnt = next - base;
    int pb = pbase[b];
    int pcnt = pbtot[b];
    int node = (b << 8) + t;
    int pp = (node < N_NODES) ? ppos[node] : 0;
    lcur[t] = pp;
    if (node < N_NODES) prowst[node] = pb + pp;
    __syncthreads();
    if (pcnt <= LCAP2) {
        for (int i = t; i < pcnt; i += 256) lcsr[i] = SENTINEL;
        __syncthreads();
        for (int i = t; i < cnt; i += 256) {
            uint32_t pk = packed[base + i];
            int pos = atomicAdd(&lcur[pk & 255u], 1);
            lcsr[pos] = (int)(pk >> 8);
        }
        __syncthreads();
        for (int i = t; i < pcnt; i += 256) csr[pb + i] = lcsr[i];
    } else {  // statistically unreachable
        for (int i = t; i < pcnt; i += 256) csr[pb + i] = SENTINEL;
        __syncthreads();
        for (int i = t; i < cnt; i += 256) {
            uint32_t pk = packed[base + i];
            int pos = atomicAdd(&lcur[pk & 255u], 1);
            csr[pb + pos] = (int)(pk >> 8);
        }
    }
}

// ---------------- dtype prep: x -> bf16 copy (GEMM) + fp8 copy (gather) ----------------

__global__ void cast_x_k(const float* __restrict__ x, uint16_t* __restrict__ xb,
                         uint32_t* __restrict__ xf8) {
    int i = blockIdx.x * blockDim.x + threadIdx.x;   // 8 floats per thread
    if (blockIdx.x == 0 && threadIdx.x < 32)
        xf8[N_NODES * 32 + threadIdx.x] = 0u;        // sentinel zero row
    if (i >= N_NODES * IN_DIM / 8) return;
    const float4* xv = (const float4*)x;
    float4 v0 = xv[2 * i], v1 = xv[2 * i + 1];
    union { uint16_t u[8]; uint4 q; } o;
    o.u[0] = f_to_bf16(v0.x); o.u[1] = f_to_bf16(v0.y);
    o.u[2] = f_to_bf16(v0.z); o.u[3] = f_to_bf16(v0.w);
    o.u[4] = f_to_bf16(v1.x); o.u[5] = f_to_bf16(v1.y);
    o.u[6] = f_to_bf16(v1.z); o.u[7] = f_to_bf16(v1.w);
    ((uint4*)xb)[i] = o.q;
    int p0 = __builtin_amdgcn_cvt_pk_fp8_f32(v0.x, v0.y, 0, false);
    p0 = __builtin_amdgcn_cvt_pk_fp8_f32(v0.z, v0.w, p0, true);
    int p1 = __builtin_amdgcn_cvt_pk_fp8_f32(v1.x, v1.y, 0, false);
    p1 = __builtin_amdgcn_cvt_pk_fp8_f32(v1.z, v1.w, p1, true);
    uint2 w2; w2.x = (uint32_t)p0; w2.y = (uint32_t)p1;
    ((uint2*)xf8)[i] = w2;
}

__global__ void prep_w_k(const float* __restrict__ W1l, const float* __restrict__ W1r,
                         const float* __restrict__ W2l, const float* __restrict__ W2r,
                         uint16_t* __restrict__ wT1, uint16_t* __restrict__ wT2) {
    int i = blockIdx.x * blockDim.x + threadIdx.x;
    if (i < 128 * 256) {
        int n = i >> 8, k = i & 255;
        float v = (k < 128) ? W1l[k * 128 + n] : W1r[(k - 128) * 128 + n];
        wT1[i] = f_to_bf16(v);
    } else {
        int j = i - 128 * 256;
        if (j < 128 * 128) {
            int n = j >> 7, k = j & 127;
            float v = (n < 64) ? W2l[k * 64 + n] : W2r[k * 64 + (n - 64)];
            wT2[j] = f_to_bf16(v);
        }
    }
}

// ---------------- layer-1 mean aggregation, fp8 gather, branch-free ----------------
// wave = 1 node; padded deg (mult of 16). 32 lanes/row (uint32 = 4 fp8);
// 8 slots x 2 rows = 16 rows (2KB) in flight, zero predication.

__global__ void aggregate_k(const int* __restrict__ csr, const int* __restrict__ prowst,
                            const int* __restrict__ deg,
                            const uint32_t* __restrict__ inf8, uint32_t* __restrict__ out2) {
    int gw = (blockIdx.x * blockDim.x + threadIdx.x) >> 6;
    int lane = threadIdx.x & 63;
    int start = prowst[gw];
    int d = deg[gw];
    int pd = (d + 15) & ~15;
    int c = lane & 31, p = lane >> 5;
    f32x2 s01 = (f32x2){0.f, 0.f}, s23 = (f32x2){0.f, 0.f};
    for (int j = 0; j < pd; j += 16) {
        uint32_t q[8];
#pragma unroll
        for (int u = 0; u < 8; u++) {
            int s = csr[start + j + 2 * u + p];
            q[u] = inf8[(s << 5) + c];
        }
#pragma unroll
        for (int u = 0; u < 8; u++) {
            s01 += __builtin_amdgcn_cvt_pk_f32_fp8((int)q[u], false);
            s23 += __builtin_amdgcn_cvt_pk_f32_fp8((int)q[u], true);
        }
    }
    float a0 = s01[0], a1 = s01[1], a2 = s23[0], a3 = s23[1];
    a0 += __shfl_xor(a0, 32, 64);
    a1 += __shfl_xor(a1, 32, 64);
    a2 += __shfl_xor(a2, 32, 64);
    a3 += __shfl_xor(a3, 32, 64);
    if (p == 0) {
        float inv = 1.0f / (float)(d > 0 ? d : 1);
        uint2 o;
        o.x = pack_bf16x2(a0 * inv, a1 * inv);
        o.y = pack_bf16x2(a2 * inv, a3 * inv);
        ((uint2*)out2)[(size_t)gw * 32 + c] = o;
    }
}

// ---------------- layer-1 GEMM: [aggr | x] (M x 256) @ wT1 (128 x 256)^T ----------------
// 2 row-stripes (32 rows) per wave; B fragments reused across stripes.
// mfma_f32_16x16x32_bf16: A lane m=lane&15, k=quad*8+j ; C/D: col=lane&15, row=quad*4+reg

__global__ __launch_bounds__(256) void gemm1_k(const uint16_t* __restrict__ ab,
                                               const uint16_t* __restrict__ xb,
                                               const uint16_t* __restrict__ wT1,
                                               const float* __restrict__ b1,
                                               uint16_t* __restrict__ hb) {
    int wave = (blockIdx.x * 256 + threadIdx.x) >> 6;
    int lane = threadIdx.x & 63;
    int m0 = wave * 32;
    if (m0 >= N_NODES) return;
    int mr = lane & 15, quad = lane >> 4;

    const uint16_t* A1s0 = ab + (size_t)(m0 + mr) * 128 + quad * 8;
    const uint16_t* A2s0 = xb + (size_t)(m0 + mr) * 128 + quad * 8;
    const uint16_t* A1s1 = A1s0 + 16 * 128;
    const uint16_t* A2s1 = A2s0 + 16 * 128;

    f32x4 acc[8][2];
#pragma unroll
    for (int nt = 0; nt < 8; nt++) {
        acc[nt][0] = (f32x4){0.f, 0.f, 0.f, 0.f};
        acc[nt][1] = (f32x4){0.f, 0.f, 0.f, 0.f};
    }

#pragma unroll
    for (int kt = 0; kt < 8; kt++) {
        const uint16_t* ap0 = (kt < 4) ? (A1s0 + kt * 32) : (A2s0 + (kt - 4) * 32);
        const uint16_t* ap1 = (kt < 4) ? (A1s1 + kt * 32) : (A2s1 + (kt - 4) * 32);
        bf16x8 a0 = *reinterpret_cast<const bf16x8*>(ap0);
        bf16x8 a1 = *reinterpret_cast<const bf16x8*>(ap1);
#pragma unroll
        for (int nt = 0; nt < 8; nt++) {
            const uint16_t* bp = wT1 + (size_t)(nt * 16 + mr) * 256 + kt * 32 + quad * 8;
            bf16x8 b = *reinterpret_cast<const bf16x8*>(bp);
            acc[nt][0] = __builtin_amdgcn_mfma_f32_16x16x32_bf16(a0, b, acc[nt][0], 0, 0, 0);
            acc[nt][1] = __builtin_amdgcn_mfma_f32_16x16x32_bf16(a1, b, acc[nt][1], 0, 0, 0);
        }
    }

#pragma unroll
    for (int nt = 0; nt < 8; nt++) {
        int col = nt * 16 + mr;
        float bias = b1[col];
#pragma unroll
        for (int s = 0; s < 2; s++) {
#pragma unroll
            for (int r = 0; r < 4; r++) {
                int row = m0 + s * 16 + quad * 4 + r;
                float v = acc[nt][s][r] + bias;
                v = v > 0.f ? v : 0.f;
                hb[(size_t)row * 128 + col] = f_to_bf16(v);
            }
        }
    }
}

// ---------------- layer-2 GEMM: h (M x 128) @ wT2 (128 x 128)^T ----------------
// cols 0..63 -> g = h@W2l (fp8, gathered by agg2); cols 64..127 -> z = h@W2r + b2 (bf16)

__global__ __launch_bounds__(256) void gemm2_k(const uint16_t* __restrict__ hb,
                                               const uint16_t* __restrict__ wT2,
                                               const float* __restrict__ b2,
                                               uint8_t* __restrict__ g,
                                               uint16_t* __restrict__ z) {
    if (blockIdx.x == 0 && threadIdx.x < 16)
        ((uint32_t*)(g + (size_t)N_NODES * 64))[threadIdx.x] = 0u;  // sentinel zero row
    int wave = (blockIdx.x * 256 + threadIdx.x) >> 6;
    int lane = threadIdx.x & 63;
    int m0 = wave * 32;
    if (m0 >= N_NODES) return;
    int mr = lane & 15, quad = lane >> 4;

    const uint16_t* As0 = hb + (size_t)(m0 + mr) * 128 + quad * 8;
    const uint16_t* As1 = As0 + 16 * 128;

    f32x4 acc[8][2];
#pragma unroll
    for (int nt = 0; nt < 8; nt++) {
        acc[nt][0] = (f32x4){0.f, 0.f, 0.f, 0.f};
        acc[nt][1] = (f32x4){0.f, 0.f, 0.f, 0.f};
    }

#pragma unroll
    for (int kt = 0; kt < 4; kt++) {
        bf16x8 a0 = *reinterpret_cast<const bf16x8*>(As0 + kt * 32);
        bf16x8 a1 = *reinterpret_cast<const bf16x8*>(As1 + kt * 32);
#pragma unroll
        for (int nt = 0; nt < 8; nt++) {
            const uint16_t* bp = wT2 + (size_t)(nt * 16 + mr) * 128 + kt * 32 + quad * 8;
            bf16x8 b = *reinterpret_cast<const bf16x8*>(bp);
            acc[nt][0] = __builtin_amdgcn_mfma_f32_16x16x32_bf16(a0, b, acc[nt][0], 0, 0, 0);
            acc[nt][1] = __builtin_amdgcn_mfma_f32_16x16x32_bf16(a1, b, acc[nt][1], 0, 0, 0);
        }
    }

#pragma unroll
    for (int nt = 0; nt < 8; nt++) {
        int col = nt * 16 + mr;
#pragma unroll
        for (int s = 0; s < 2; s++) {
#pragma unroll
            for (int r = 0; r < 4; r++) {
                int row = m0 + s * 16 + quad * 4 + r;
                if (nt < 4) {
                    float v = acc[nt][s][r];
                    int pk = __builtin_amdgcn_cvt_pk_fp8_f32(v, v, 0, false);
                    g[(size_t)row * 64 + col] = (uint8_t)(pk & 0xff);
                } else {
                    z[(size_t)row * 64 + (col - 64)] = f_to_bf16(acc[nt][s][r] + b2[col - 64]);
                }
            }
        }
    }
}

// ---------------- layer-2 aggregation, fp8 gather (64 B rows), branch-free ----------------
// wave = 1 node. 16 lanes/row (uint32); 4 rows per slot, 4 slots = 16 rows/iter.

__global__ void agg2_k(const int* __restrict__ csr, const int* __restrict__ prowst,
                       const int* __restrict__ deg,
                       const uint32_t* __restrict__ g4, const uint16_t* __restrict__ z,
                       float* __restrict__ out) {
    int w = (blockIdx.x * blockDim.x + threadIdx.x) >> 6;
    int lane = threadIdx.x & 63;
    int start = prowst[w];
    int d = deg[w];
    int pd = (d + 15) & ~15;
    int c = lane & 15, p = lane >> 4;
    f32x2 s01 = (f32x2){0.f, 0.f}, s23 = (f32x2){0.f, 0.f};
    for (int j = 0; j < pd; j += 16) {
        uint32_t q[4];
#pragma unroll
        for (int u = 0; u < 4; u++) {
            int s = csr[start + j + 4 * u + p];
            q[u] = g4[(s << 4) + c];
        }
#pragma unroll
        for (int u = 0; u < 4; u++) {
            s01 += __builtin_amdgcn_cvt_pk_f32_fp8((int)q[u], false);
            s23 += __builtin_amdgcn_cvt_pk_f32_fp8((int)q[u], true);
        }
    }
    float a0 = s01[0], a1 = s01[1], a2 = s23[0], a3 = s23[1];
    a0 += __shfl_xor(a0, 16, 64); a0 += __shfl_xor(a0, 32, 64);
    a1 += __shfl_xor(a1, 16, 64); a1 += __shfl_xor(a1, 32, 64);
    a2 += __shfl_xor(a2, 16, 64); a2 += __shfl_xor(a2, 32, 64);
    a3 += __shfl_xor(a3, 16, 64); a3 += __shfl_xor(a3, 32, 64);
    if (p == 0) {
        float inv = 1.0f / (float)(d > 0 ? d : 1);
        uint2 zq = ((const uint2*)z)[(size_t)w * 16 + c];
        float4 o;
        o.x = a0 * inv + bf16lo_f(zq.x);
        o.y = a1 * inv + bf16hi_f(zq.x);
        o.z = a2 * inv + bf16lo_f(zq.y);
        o.w = a3 * inv + bf16hi_f(zq.y);
        ((float4*)out)[(size_t)w * 16 + c] = o;
    }
}

// ---------------- launch ----------------

extern "C" void kernel_launch(void* const* d_in, const int* in_sizes, int n_in,
                              void* d_out, int out_size, void* d_ws, size_t ws_size,
                              hipStream_t stream) {
    const float* x   = (const float*)d_in[0];
    const int*  ei   = (const int*)d_in[1];
    const float* W1l = (const float*)d_in[2];
    const float* b1  = (const float*)d_in[3];
    const float* W1r = (const float*)d_in[4];
    const float* W2l = (const float*)d_in[5];
    const float* b2  = (const float*)d_in[6];
    const float* W2r = (const float*)d_in[7];
    float* out = (float*)d_out;

    const int* srcv = ei;            // edge_index[0]
    const int* dstv = ei + N_EDGES;  // edge_index[1]

    char* ws = (char*)d_ws;
    int*      deg      = (int*)(ws + 0);              // 100000 ints
    int*      prowst   = (int*)(ws + 401408);         // 100000 ints (padded row starts)
    int*      ppos     = (int*)(ws + 802816);         // 100000 ints
    int*      partials = (int*)(ws + 1204224);        // 150 ints
    int*      pbtot    = (int*)(ws + 1205248);        // 391 ints
    int*      pbase    = (int*)(ws + 1207296);        // 391 ints
    int*      csr      = (int*)(ws + 1209344);        // padded csr, <=3.1M ints (12.6MB)
    uint16_t* wT1      = (uint16_t*)(ws + 13809664);  // 64 KB
    uint16_t* wT2      = (uint16_t*)(ws + 13875200);  // 32 KB
    uint16_t* xb       = (uint16_t*)(ws + 13907968);  // 25.6 MB -> 39507968
    char*     abreg    = (ws + 39507968);             // 25.6 MB region -> 65107968
    uint16_t* hb       = (uint16_t*)(ws + 65107968);  // 25.6 MB -> 90707968
    // ab region during layer 1 = full bf16 aggregate (25.6MB); reused by gemm2 outputs:
    uint16_t* ab       = (uint16_t*)abreg;
    uint16_t* z        = (uint16_t*)abreg;                    // 12.8 MB bf16
    uint8_t*  g        = (uint8_t*)(abreg + 12800000);        // 6.4 MB + 64 fp8
    // aliases into hb region (consumed before gemm1 writes hb; stream-ordered):
    uint32_t* packed   = (uint32_t*)hb;                       // 6.4 MB
    int*      hoff     = (int*)(ws + 65107968 + 6400000);     // 611 KB
    uint32_t* xf8      = (uint32_t*)(ws + 65107968 + 7013376);// 12.8 MB + 128

    // graph build (no global atomics), padded CSR
    hist1_k<<<NBE, 256, 0, stream>>>(dstv, hoff);
    scan1_k<<<NB_SCAN, 256, 0, stream>>>(hoff, partials, HM);
    scan2_k<<<1, 256, 0, stream>>>(partials, NB_SCAN);
    scan3_k<<<(HM + 255) / 256, 256, 0, stream>>>(hoff, partials, HM);
    scatter2_k<<<NBE, 256, 0, stream>>>(srcv, dstv, hoff, packed);
    bhist_k<<<NBUCKET, 256, 0, stream>>>(packed, hoff, deg, ppos, pbtot);
    pscan_k<<<1, 512, 0, stream>>>(pbtot, pbase);
    pscatter_k<<<NBUCKET, 256, 0, stream>>>(packed, hoff, ppos, pbtot, pbase, csr, prowst);

    // dtype prep
    cast_x_k<<<6250, 256, 0, stream>>>(x, xb, xf8);
    prep_w_k<<<192, 256, 0, stream>>>(W1l, W1r, W2l, W2r, wT1, wT2);

    // layer 1: aggr(x_fp8) -> ab(bf16) ; h = relu([ab|x] @ wT1^T + b1) -> hb
    aggregate_k<<<25000, 256, 0, stream>>>(csr, prowst, deg, xf8, (uint32_t*)ab);
    gemm1_k<<<782, 256, 0, stream>>>(ab, xb, wT1, b1, hb);

    // layer 2: [g|z] = h @ [W2l|W2r] (+b2 on z), g fp8 / z bf16 ; out = mean-aggr(g) + z
    gemm2_k<<<782, 256, 0, stream>>>(hb, wT2, b2, g, z);
    agg2_k<<<25000, 256, 0, stream>>>(csr, prowst, deg, (const uint32_t*)g, z, out);
}

// Round 7
// 291.059 us; speedup vs baseline: 3.4242x; 1.0680x over previous
//
#include <hip/hip_runtime.h>
#include <hip/hip_bf16.h>
#include <stdint.h>

#define N_NODES 100000
#define N_EDGES 1600000
#define IN_DIM 128
#define HID_DIM 128
#define OUT_DIM 64
#define NBUCKET 391   // ceil(N_NODES/256), bucket = dst>>8
#define NBE 391       // edge blocks, 4096 edges each
#define ECHUNK 4096
#define HM (NBUCKET * NBE)          // 152881 hist entries
#define NB_SCAN 150                 // ceil(HM/1024)
#define SENTINEL N_NODES            // padded-slot src -> zero row

typedef __bf16 bf16x8 __attribute__((ext_vector_type(8)));
typedef float f32x4 __attribute__((ext_vector_type(4)));
typedef float f32x2 __attribute__((ext_vector_type(2)));

__device__ __forceinline__ uint16_t f_to_bf16(float f) {
    uint32_t u = __float_as_uint(f);
    u += 0x7fffu + ((u >> 16) & 1u);   // round-to-nearest-even
    return (uint16_t)(u >> 16);
}
__device__ __forceinline__ uint32_t pack_bf16x2(float lo, float hi) {
    return (uint32_t)f_to_bf16(lo) | ((uint32_t)f_to_bf16(hi) << 16);
}

// ---------------- graph build: atomic-free two-pass radix partition ----------------

__global__ __launch_bounds__(256) void hist1_k(const int* __restrict__ dst,
                                               int* __restrict__ hist) {
    __shared__ int lh[NBUCKET];
    int blk = blockIdx.x, t = threadIdx.x;
    for (int i = t; i < NBUCKET; i += 256) lh[i] = 0;
    __syncthreads();
    int e0 = blk * ECHUNK;
    int e1 = e0 + ECHUNK; if (e1 > N_EDGES) e1 = N_EDGES;
    for (int e = e0 + t; e < e1; e += 256) atomicAdd(&lh[dst[e] >> 8], 1);
    __syncthreads();
    for (int i = t; i < NBUCKET; i += 256) hist[i * NBE + blk] = lh[i];
}

__global__ void scan1_k(int* __restrict__ data, int* __restrict__ partials, int n) {
    __shared__ int sm[256];
    int tid = threadIdx.x;
    int base = blockIdx.x * 1024 + tid * 4;
    int v0 = 0, v1 = 0, v2 = 0, v3 = 0;
    if (base + 0 < n) v0 = data[base + 0];
    if (base + 1 < n) v1 = data[base + 1];
    if (base + 2 < n) v2 = data[base + 2];
    if (base + 3 < n) v3 = data[base + 3];
    int tot = v0 + v1 + v2 + v3;
    sm[tid] = tot;
    __syncthreads();
    int val = tot;
    for (int off = 1; off < 256; off <<= 1) {
        int x = (tid >= off) ? sm[tid - off] : 0;
        __syncthreads();
        val += x;
        sm[tid] = val;
        __syncthreads();
    }
    int excl = val - tot;
    if (tid == 255) partials[blockIdx.x] = val;
    if (base + 0 < n) data[base + 0] = excl;
    if (base + 1 < n) data[base + 1] = excl + v0;
    if (base + 2 < n) data[base + 2] = excl + v0 + v1;
    if (base + 3 < n) data[base + 3] = excl + v0 + v1 + v2;
}

__global__ void scan2_k(int* __restrict__ partials, int nb) {
    __shared__ int sm[256];
    int tid = threadIdx.x;
    int v = (tid < nb) ? partials[tid] : 0;
    sm[tid] = v;
    __syncthreads();
    int val = v;
    for (int off = 1; off < 256; off <<= 1) {
        int x = (tid >= off) ? sm[tid - off] : 0;
        __syncthreads();
        val += x;
        sm[tid] = val;
        __syncthreads();
    }
    if (tid < nb) partials[tid] = val - v;  // exclusive
}

__global__ void scan3_k(int* __restrict__ data, const int* __restrict__ partials, int n) {
    int i = blockIdx.x * blockDim.x + threadIdx.x;
    if (i < n) data[i] += partials[i >> 10];
}

__global__ __launch_bounds__(256) void scatter2_k(const int* __restrict__ src,
                                                  const int* __restrict__ dst,
                                                  const int* __restrict__ hoff,
                                                  uint32_t* __restrict__ packed) {
    __shared__ int loff[NBUCKET];
    int blk = blockIdx.x, t = threadIdx.x;
    for (int i = t; i < NBUCKET; i += 256) loff[i] = hoff[i * NBE + blk];
    __syncthreads();
    int e0 = blk * ECHUNK;
    int e1 = e0 + ECHUNK; if (e1 > N_EDGES) e1 = N_EDGES;
    for (int e = e0 + t; e < e1; e += 256) {
        int d = dst[e];
        int pos = atomicAdd(&loff[d >> 8], 1);
        packed[pos] = ((uint32_t)src[e] << 8) | (uint32_t)(d & 255);
    }
}

// per-bucket node histogram -> deg, per-node padded excl scan -> ppos, bucket padded total
__global__ __launch_bounds__(256) void bhist_k(const uint32_t* __restrict__ packed,
                                               const int* __restrict__ hoff,
                                               int* __restrict__ deg,
                                               int* __restrict__ ppos,
                                               int* __restrict__ pbtot) {
    __shared__ int lhist[256];
    __shared__ int ssc[256];
    int b = blockIdx.x, t = threadIdx.x;
    int base = hoff[b * NBE];
    int next = (b + 1 < NBUCKET) ? hoff[(b + 1) * NBE] : N_EDGES;
    int cnt = next - base;
    lhist[t] = 0;
    __syncthreads();
    for (int i = t; i < cnt; i += 256) atomicAdd(&lhist[packed[base + i] & 255u], 1);
    __syncthreads();
    int d = lhist[t];
    int pd = (d + 15) & ~15;
    ssc[t] = pd;
    __syncthreads();
    int val = pd;
    for (int off = 1; off < 256; off <<= 1) {
        int x = (t >= off) ? ssc[t - off] : 0;
        __syncthreads();
        val += x;
        ssc[t] = val;
        __syncthreads();
    }
    int node = (b << 8) + t;
    if (node < N_NODES) { deg[node] = d; ppos[node] = val - pd; }
    if (t == 255) pbtot[b] = val;
}

// exclusive scan of 391 padded bucket totals
__global__ void pscan_k(const int* __restrict__ pbtot, int* __restrict__ pbase) {
    __shared__ int sm[512];
    int t = threadIdx.x;
    int v = (t < NBUCKET) ? pbtot[t] : 0;
    sm[t] = v;
    __syncthreads();
    int val = v;
    for (int off = 1; off < 512; off <<= 1) {
        int x = (t >= off) ? sm[t - off] : 0;
        __syncthreads();
        val += x;
        sm[t] = val;
        __syncthreads();
    }
    if (t < NBUCKET) pbase[t] = val - v;
}

// padded CSR scatter: sentinel-filled pads, per-node padded row starts
#define LCAP2 8192
__global__ __launch_bounds__(256) void pscatter_k(const uint32_t* __restrict__ packed,
                                                  const int* __restrict__ hoff,
                                                  const int* __restrict__ ppos,
                                                  const int* __restrict__ pbtot,
                                                  const int* __restrict__ pbase,
                                                  int* __restrict__ csr,
                                                  int* __restrict__ prowst) {
    __shared__ int lcur[256];
    __shared__ int lcsr[LCAP2];
    int b = blockIdx.x, t = threadIdx.x;
    int base = hoff[b * NBE];
    int next = (b + 1 < NBUCKET) ? hoff[(b + 1) * NBE] : N_EDGES;
    int cnt = next - base;
    int pb = pbase[b];
    int pcnt = pbtot[b];
    int node = (b << 8) + t;
    int pp = (node < N_NODES) ? ppos[node] : 0;
    lcur[t] = pp;
    if (node < N_NODES) prowst[node] = pb + pp;
    __syncthreads();
    if (pcnt <= LCAP2) {
        for (int i = t; i < pcnt; i += 256) lcsr[i] = SENTINEL;
        __syncthreads();
        for (int i = t; i < cnt; i += 256) {
            uint32_t pk = packed[base + i];
            int pos = atomicAdd(&lcur[pk & 255u], 1);
            lcsr[pos] = (int)(pk >> 8);
        }
        __syncthreads();
        for (int i = t; i < pcnt; i += 256) csr[pb + i] = lcsr[i];
    } else {  // statistically unreachable
        for (int i = t; i < pcnt; i += 256) csr[pb + i] = SENTINEL;
        __syncthreads();
        for (int i = t; i < cnt; i += 256) {
            uint32_t pk = packed[base + i];
            int pos = atomicAdd(&lcur[pk & 255u], 1);
            csr[pb + pos] = (int)(pk >> 8);
        }
    }
}

// ---------------- dtype prep: x -> bf16 copy (GEMM) + fp8 copy (gather) ----------------

__global__ void cast_x_k(const float* __restrict__ x, uint16_t* __restrict__ xb,
                         uint32_t* __restrict__ xf8) {
    int i = blockIdx.x * blockDim.x + threadIdx.x;   // 8 floats per thread
    if (blockIdx.x == 0 && threadIdx.x < 32)
        xf8[N_NODES * 32 + threadIdx.x] = 0u;        // sentinel zero row
    if (i >= N_NODES * IN_DIM / 8) return;
    const float4* xv = (const float4*)x;
    float4 v0 = xv[2 * i], v1 = xv[2 * i + 1];
    union { uint16_t u[8]; uint4 q; } o;
    o.u[0] = f_to_bf16(v0.x); o.u[1] = f_to_bf16(v0.y);
    o.u[2] = f_to_bf16(v0.z); o.u[3] = f_to_bf16(v0.w);
    o.u[4] = f_to_bf16(v1.x); o.u[5] = f_to_bf16(v1.y);
    o.u[6] = f_to_bf16(v1.z); o.u[7] = f_to_bf16(v1.w);
    ((uint4*)xb)[i] = o.q;
    int p0 = __builtin_amdgcn_cvt_pk_fp8_f32(v0.x, v0.y, 0, false);
    p0 = __builtin_amdgcn_cvt_pk_fp8_f32(v0.z, v0.w, p0, true);
    int p1 = __builtin_amdgcn_cvt_pk_fp8_f32(v1.x, v1.y, 0, false);
    p1 = __builtin_amdgcn_cvt_pk_fp8_f32(v1.z, v1.w, p1, true);
    uint2 w2; w2.x = (uint32_t)p0; w2.y = (uint32_t)p1;
    ((uint2*)xf8)[i] = w2;
}

__global__ void prep_w_k(const float* __restrict__ W1l, const float* __restrict__ W1r,
                         const float* __restrict__ W2l, const float* __restrict__ W2r,
                         uint16_t* __restrict__ wT1, uint16_t* __restrict__ wT2) {
    int i = blockIdx.x * blockDim.x + threadIdx.x;
    if (i < 128 * 256) {
        int n = i >> 8, k = i & 255;
        float v = (k < 128) ? W1l[k * 128 + n] : W1r[(k - 128) * 128 + n];
        wT1[i] = f_to_bf16(v);
    } else {
        int j = i - 128 * 256;
        if (j < 128 * 128) {
            int n = j >> 7, k = j & 127;
            float v = (n < 64) ? W2l[k * 64 + n] : W2r[k * 64 + (n - 64)];
            wT2[j] = f_to_bf16(v);
        }
    }
}

// ---------------- layer-1 mean aggregation, fp8 gather, branch-free ----------------

__global__ void aggregate_k(const int* __restrict__ csr, const int* __restrict__ prowst,
                            const int* __restrict__ deg,
                            const uint32_t* __restrict__ inf8, uint32_t* __restrict__ out2) {
    int gw = (blockIdx.x * blockDim.x + threadIdx.x) >> 6;
    int lane = threadIdx.x & 63;
    int start = prowst[gw];
    int d = deg[gw];
    int pd = (d + 15) & ~15;
    int c = lane & 31, p = lane >> 5;
    f32x2 s01 = (f32x2){0.f, 0.f}, s23 = (f32x2){0.f, 0.f};
    for (int j = 0; j < pd; j += 16) {
        uint32_t q[8];
#pragma unroll
        for (int u = 0; u < 8; u++) {
            int s = csr[start + j + 2 * u + p];
            q[u] = inf8[(s << 5) + c];
        }
#pragma unroll
        for (int u = 0; u < 8; u++) {
            s01 += __builtin_amdgcn_cvt_pk_f32_fp8((int)q[u], false);
            s23 += __builtin_amdgcn_cvt_pk_f32_fp8((int)q[u], true);
        }
    }
    float a0 = s01[0], a1 = s01[1], a2 = s23[0], a3 = s23[1];
    a0 += __shfl_xor(a0, 32, 64);
    a1 += __shfl_xor(a1, 32, 64);
    a2 += __shfl_xor(a2, 32, 64);
    a3 += __shfl_xor(a3, 32, 64);
    if (p == 0) {
        float inv = 1.0f / (float)(d > 0 ? d : 1);
        uint2 o;
        o.x = pack_bf16x2(a0 * inv, a1 * inv);
        o.y = pack_bf16x2(a2 * inv, a3 * inv);
        ((uint2*)out2)[(size_t)gw * 32 + c] = o;
    }
}

// ---------------- layer-1 GEMM: [aggr | x] (M x 256) @ wT1 (128 x 256)^T ----------------
// Block: 256 thr stages wT1 (64KB) in LDS (xor-swizzled); 4 waves x 64 rows = 256 rows.
// mfma_f32_16x16x32_bf16: A lane m=lane&15, k=quad*8+j ; C/D: col=lane&15, row=quad*4+reg

__global__ __launch_bounds__(256, 2) void gemm1_k(const uint16_t* __restrict__ ab,
                                                  const uint16_t* __restrict__ xb,
                                                  const uint16_t* __restrict__ wT1,
                                                  const float* __restrict__ b1,
                                                  uint16_t* __restrict__ hb) {
    __shared__ uint16_t lw[128 * 256];   // 64 KB
    int t = threadIdx.x;
    {   // stage: global chunk i = (row r = i>>5, chunk cc = i&31) -> lds chunk r*32 + (cc^(r&31))
        const uint4* gsrc = (const uint4*)wT1;
        uint4* ldst = (uint4*)lw;
        for (int i = t; i < 4096; i += 256) {
            int r = i >> 5, cc = i & 31;
            ldst[(r << 5) + (cc ^ (r & 31))] = gsrc[i];
        }
    }
    __syncthreads();

    int wave = t >> 6;
    int lane = t & 63;
    int m0 = blockIdx.x * 256 + wave * 64;
    int mr = lane & 15, quad = lane >> 4;

    const uint16_t* A1[4];
    const uint16_t* A2[4];
#pragma unroll
    for (int s = 0; s < 4; s++) {
        int row = m0 + s * 16 + mr;
        if (row > N_NODES - 1) row = N_NODES - 1;   // clamp (stores still guarded)
        A1[s] = ab + (size_t)row * 128 + quad * 8;
        A2[s] = xb + (size_t)row * 128 + quad * 8;
    }

    f32x4 acc[8][4];
#pragma unroll
    for (int nt = 0; nt < 8; nt++)
#pragma unroll
        for (int s = 0; s < 4; s++) acc[nt][s] = (f32x4){0.f, 0.f, 0.f, 0.f};

#pragma unroll
    for (int kt = 0; kt < 8; kt++) {
        bf16x8 av[4];
#pragma unroll
        for (int s = 0; s < 4; s++) {
            const uint16_t* ap = (kt < 4) ? (A1[s] + kt * 32) : (A2[s] + (kt - 4) * 32);
            av[s] = *reinterpret_cast<const bf16x8*>(ap);
        }
#pragma unroll
        for (int nt = 0; nt < 8; nt++) {
            int brow = nt * 16 + mr;
            int chunk = kt * 4 + quad;
            const uint16_t* bp = lw + (brow << 8) + ((chunk ^ (brow & 31)) << 3);
            bf16x8 b = *reinterpret_cast<const bf16x8*>(bp);
#pragma unroll
            for (int s = 0; s < 4; s++)
                acc[nt][s] = __builtin_amdgcn_mfma_f32_16x16x32_bf16(av[s], b, acc[nt][s], 0, 0, 0);
        }
    }

#pragma unroll
    for (int nt = 0; nt < 8; nt++) {
        int col = nt * 16 + mr;
        float bias = b1[col];
#pragma unroll
        for (int s = 0; s < 4; s++) {
#pragma unroll
            for (int r = 0; r < 4; r++) {
                int row = m0 + s * 16 + quad * 4 + r;
                if (row < N_NODES) {
                    float v = acc[nt][s][r] + bias;
                    v = v > 0.f ? v : 0.f;
                    hb[(size_t)row * 128 + col] = f_to_bf16(v);
                }
            }
        }
    }
}

// ---------------- layer-2 GEMM: h (M x 128) @ wT2 (128 x 128)^T ----------------
// cols 0..63 -> g = h@W2l (fp8); cols 64..127 -> z = h@W2r + b2 (fp32)

__global__ __launch_bounds__(256, 2) void gemm2_k(const uint16_t* __restrict__ hb,
                                                  const uint16_t* __restrict__ wT2,
                                                  const float* __restrict__ b2,
                                                  uint8_t* __restrict__ g,
                                                  float* __restrict__ z) {
    __shared__ uint16_t lw[128 * 128];   // 32 KB
    int t = threadIdx.x;
    if (blockIdx.x == 0 && t < 16)
        ((uint32_t*)(g + (size_t)N_NODES * 64))[t] = 0u;  // sentinel zero row
    {   // stage: chunk i = (r = i>>4, cc = i&15) -> lds chunk r*16 + (cc^(r&15))
        const uint4* gsrc = (const uint4*)wT2;
        uint4* ldst = (uint4*)lw;
        for (int i = t; i < 2048; i += 256) {
            int r = i >> 4, cc = i & 15;
            ldst[(r << 4) + (cc ^ (r & 15))] = gsrc[i];
        }
    }
    __syncthreads();

    int wave = t >> 6;
    int lane = t & 63;
    int m0 = blockIdx.x * 256 + wave * 64;
    int mr = lane & 15, quad = lane >> 4;

    const uint16_t* A[4];
#pragma unroll
    for (int s = 0; s < 4; s++) {
        int row = m0 + s * 16 + mr;
        if (row > N_NODES - 1) row = N_NODES - 1;
        A[s] = hb + (size_t)row * 128 + quad * 8;
    }

    f32x4 acc[8][4];
#pragma unroll
    for (int nt = 0; nt < 8; nt++)
#pragma unroll
        for (int s = 0; s < 4; s++) acc[nt][s] = (f32x4){0.f, 0.f, 0.f, 0.f};

#pragma unroll
    for (int kt = 0; kt < 4; kt++) {
        bf16x8 av[4];
#pragma unroll
        for (int s = 0; s < 4; s++)
            av[s] = *reinterpret_cast<const bf16x8*>(A[s] + kt * 32);
#pragma unroll
        for (int nt = 0; nt < 8; nt++) {
            int brow = nt * 16 + mr;
            int chunk = kt * 4 + quad;
            const uint16_t* bp = lw + (brow << 7) + ((chunk ^ (brow & 15)) << 3);
            bf16x8 b = *reinterpret_cast<const bf16x8*>(bp);
#pragma unroll
            for (int s = 0; s < 4; s++)
                acc[nt][s] = __builtin_amdgcn_mfma_f32_16x16x32_bf16(av[s], b, acc[nt][s], 0, 0, 0);
        }
    }

#pragma unroll
    for (int nt = 0; nt < 8; nt++) {
        int col = nt * 16 + mr;
#pragma unroll
        for (int s = 0; s < 4; s++) {
#pragma unroll
            for (int r = 0; r < 4; r++) {
                int row = m0 + s * 16 + quad * 4 + r;
                if (row < N_NODES) {
                    if (nt < 4) {
                        float v = acc[nt][s][r];
                        int pk = __builtin_amdgcn_cvt_pk_fp8_f32(v, v, 0, false);
                        g[(size_t)row * 64 + col] = (uint8_t)(pk & 0xff);
                    } else {
                        z[(size_t)row * 64 + (col - 64)] = acc[nt][s][r] + b2[col - 64];
                    }
                }
            }
        }
    }
}

// ---------------- layer-2 aggregation, fp8 gather (64 B rows), branch-free ----------------

__global__ void agg2_k(const int* __restrict__ csr, const int* __restrict__ prowst,
                       const int* __restrict__ deg,
                       const uint32_t* __restrict__ g4, const float* __restrict__ z,
                       float* __restrict__ out) {
    int w = (blockIdx.x * blockDim.x + threadIdx.x) >> 6;
    int lane = threadIdx.x & 63;
    int start = prowst[w];
    int d = deg[w];
    int pd = (d + 15) & ~15;
    int c = lane & 15, p = lane >> 4;
    f32x2 s01 = (f32x2){0.f, 0.f}, s23 = (f32x2){0.f, 0.f};
    for (int j = 0; j < pd; j += 16) {
        uint32_t q[4];
#pragma unroll
        for (int u = 0; u < 4; u++) {
            int s = csr[start + j + 4 * u + p];
            q[u] = g4[(s << 4) + c];
        }
#pragma unroll
        for (int u = 0; u < 4; u++) {
            s01 += __builtin_amdgcn_cvt_pk_f32_fp8((int)q[u], false);
            s23 += __builtin_amdgcn_cvt_pk_f32_fp8((int)q[u], true);
        }
    }
    float a0 = s01[0], a1 = s01[1], a2 = s23[0], a3 = s23[1];
    a0 += __shfl_xor(a0, 16, 64); a0 += __shfl_xor(a0, 32, 64);
    a1 += __shfl_xor(a1, 16, 64); a1 += __shfl_xor(a1, 32, 64);
    a2 += __shfl_xor(a2, 16, 64); a2 += __shfl_xor(a2, 32, 64);
    a3 += __shfl_xor(a3, 16, 64); a3 += __shfl_xor(a3, 32, 64);
    if (p == 0) {
        float inv = 1.0f / (float)(d > 0 ? d : 1);
        float4 zz = ((const float4*)z)[(size_t)w * 16 + c];
        float4 o;
        o.x = a0 * inv + zz.x;
        o.y = a1 * inv + zz.y;
        o.z = a2 * inv + zz.z;
        o.w = a3 * inv + zz.w;
        ((float4*)out)[(size_t)w * 16 + c] = o;
    }
}

// ---------------- launch ----------------

extern "C" void kernel_launch(void* const* d_in, const int* in_sizes, int n_in,
                              void* d_out, int out_size, void* d_ws, size_t ws_size,
                              hipStream_t stream) {
    const float* x   = (const float*)d_in[0];
    const int*  ei   = (const int*)d_in[1];
    const float* W1l = (const float*)d_in[2];
    const float* b1  = (const float*)d_in[3];
    const float* W1r = (const float*)d_in[4];
    const float* W2l = (const float*)d_in[5];
    const float* b2  = (const float*)d_in[6];
    const float* W2r = (const float*)d_in[7];
    float* out = (float*)d_out;

    const int* srcv = ei;            // edge_index[0]
    const int* dstv = ei + N_EDGES;  // edge_index[1]

    char* ws = (char*)d_ws;
    int*      deg      = (int*)(ws + 0);              // 100000 ints
    int*      prowst   = (int*)(ws + 401408);         // 100000 ints (padded row starts)
    int*      ppos     = (int*)(ws + 802816);         // 100000 ints
    int*      partials = (int*)(ws + 1204224);        // 150 ints
    int*      pbtot    = (int*)(ws + 1205248);        // 391 ints
    int*      pbase    = (int*)(ws + 1207296);        // 391 ints
    int*      csr      = (int*)(ws + 1209344);        // padded csr, <=3.1M ints (12.6MB)
    uint16_t* wT1      = (uint16_t*)(ws + 13809664);  // 64 KB
    uint16_t* wT2      = (uint16_t*)(ws + 13875200);  // 32 KB
    uint16_t* xb       = (uint16_t*)(ws + 13907968);  // 25.6 MB -> 39507968
    char*     abreg    = (ws + 39507968);             // 25.6 MB region -> 65107968
    uint16_t* hb       = (uint16_t*)(ws + 65107968);  // 25.6 MB -> 90707968
    // layer-1: abreg = bf16 aggregate; layer-2 reuse: z (fp32, 25.6MB) = abreg, g (fp8) = xb
    uint16_t* ab       = (uint16_t*)abreg;
    float*    z        = (float*)abreg;               // 25.6 MB fp32 (written by gemm2 after ab last read)
    uint8_t*  g        = (uint8_t*)xb;                // 6.4 MB + 64 (written by gemm2 after xb last read)
    // aliases into hb region (consumed before gemm1 writes hb; stream-ordered):
    uint32_t* packed   = (uint32_t*)hb;                       // 6.4 MB
    int*      hoff     = (int*)(ws + 65107968 + 6400000);     // 611 KB
    uint32_t* xf8      = (uint32_t*)(ws + 65107968 + 7013376);// 12.8 MB + 128

    // graph build (no global atomics), padded CSR
    hist1_k<<<NBE, 256, 0, stream>>>(dstv, hoff);
    scan1_k<<<NB_SCAN, 256, 0, stream>>>(hoff, partials, HM);
    scan2_k<<<1, 256, 0, stream>>>(partials, NB_SCAN);
    scan3_k<<<(HM + 255) / 256, 256, 0, stream>>>(hoff, partials, HM);
    scatter2_k<<<NBE, 256, 0, stream>>>(srcv, dstv, hoff, packed);
    bhist_k<<<NBUCKET, 256, 0, stream>>>(packed, hoff, deg, ppos, pbtot);
    pscan_k<<<1, 512, 0, stream>>>(pbtot, pbase);
    pscatter_k<<<NBUCKET, 256, 0, stream>>>(packed, hoff, ppos, pbtot, pbase, csr, prowst);

    // dtype prep
    cast_x_k<<<6250, 256, 0, stream>>>(x, xb, xf8);
    prep_w_k<<<192, 256, 0, stream>>>(W1l, W1r, W2l, W2r, wT1, wT2);

    // layer 1: aggr(x_fp8) -> ab(bf16) ; h = relu([ab|x] @ wT1^T + b1) -> hb
    aggregate_k<<<25000, 256, 0, stream>>>(csr, prowst, deg, xf8, (uint32_t*)ab);
    gemm1_k<<<391, 256, 0, stream>>>(ab, xb, wT1, b1, hb);

    // layer 2: [g|z] = h @ [W2l|W2r] (+b2 on z), g fp8 / z fp32 ; out = mean-aggr(g) + z
    gemm2_k<<<391, 256, 0, stream>>>(hb, wT2, b2, g, z);
    agg2_k<<<25000, 256, 0, stream>>>(csr, prowst, deg, (const uint32_t*)g, z, out);
}

// Round 8
// 270.111 us; speedup vs baseline: 3.6897x; 1.0776x over previous
//
#include <hip/hip_runtime.h>
#include <hip/hip_bf16.h>
#include <stdint.h>

#define N_NODES 100000
#define N_EDGES 1600000
#define IN_DIM 128
#define HID_DIM 128
#define OUT_DIM 64
#define NBUCKET 391   // ceil(N_NODES/256), bucket = dst>>8
#define NBE 391       // edge blocks, 4096 edges each
#define ECHUNK 4096
#define HM (NBUCKET * NBE)          // 152881 hist entries
#define NB_SCAN 150                 // ceil(HM/1024)
#define SENTINEL N_NODES            // padded-slot src -> zero row

typedef __bf16 bf16x8 __attribute__((ext_vector_type(8)));
typedef float f32x4 __attribute__((ext_vector_type(4)));
typedef float f32x2 __attribute__((ext_vector_type(2)));

__device__ __forceinline__ uint16_t f_to_bf16(float f) {
    uint32_t u = __float_as_uint(f);
    u += 0x7fffu + ((u >> 16) & 1u);   // round-to-nearest-even
    return (uint16_t)(u >> 16);
}
__device__ __forceinline__ uint32_t pack_bf16x2(float lo, float hi) {
    return (uint32_t)f_to_bf16(lo) | ((uint32_t)f_to_bf16(hi) << 16);
}

// ---------------- graph build: atomic-free two-pass radix partition ----------------

__global__ __launch_bounds__(256) void hist1_k(const int* __restrict__ dst,
                                               int* __restrict__ hist) {
    __shared__ int lh[NBUCKET];
    int blk = blockIdx.x, t = threadIdx.x;
    for (int i = t; i < NBUCKET; i += 256) lh[i] = 0;
    __syncthreads();
    int e0 = blk * ECHUNK;
    int e1 = e0 + ECHUNK; if (e1 > N_EDGES) e1 = N_EDGES;
    for (int e = e0 + t; e < e1; e += 256) atomicAdd(&lh[dst[e] >> 8], 1);
    __syncthreads();
    for (int i = t; i < NBUCKET; i += 256) hist[i * NBE + blk] = lh[i];
}

__global__ void scan1_k(int* __restrict__ data, int* __restrict__ partials, int n) {
    __shared__ int sm[256];
    int tid = threadIdx.x;
    int base = blockIdx.x * 1024 + tid * 4;
    int v0 = 0, v1 = 0, v2 = 0, v3 = 0;
    if (base + 0 < n) v0 = data[base + 0];
    if (base + 1 < n) v1 = data[base + 1];
    if (base + 2 < n) v2 = data[base + 2];
    if (base + 3 < n) v3 = data[base + 3];
    int tot = v0 + v1 + v2 + v3;
    sm[tid] = tot;
    __syncthreads();
    int val = tot;
    for (int off = 1; off < 256; off <<= 1) {
        int x = (tid >= off) ? sm[tid - off] : 0;
        __syncthreads();
        val += x;
        sm[tid] = val;
        __syncthreads();
    }
    int excl = val - tot;
    if (tid == 255) partials[blockIdx.x] = val;
    if (base + 0 < n) data[base + 0] = excl;
    if (base + 1 < n) data[base + 1] = excl + v0;
    if (base + 2 < n) data[base + 2] = excl + v0 + v1;
    if (base + 3 < n) data[base + 3] = excl + v0 + v1 + v2;
}

__global__ void scan2_k(int* __restrict__ partials, int nb) {
    __shared__ int sm[256];
    int tid = threadIdx.x;
    int v = (tid < nb) ? partials[tid] : 0;
    sm[tid] = v;
    __syncthreads();
    int val = v;
    for (int off = 1; off < 256; off <<= 1) {
        int x = (tid >= off) ? sm[tid - off] : 0;
        __syncthreads();
        val += x;
        sm[tid] = val;
        __syncthreads();
    }
    if (tid < nb) partials[tid] = val - v;  // exclusive
}

__global__ void scan3_k(int* __restrict__ data, const int* __restrict__ partials, int n) {
    int i = blockIdx.x * blockDim.x + threadIdx.x;
    if (i < n) data[i] += partials[i >> 10];
}

__global__ __launch_bounds__(256) void scatter2_k(const int* __restrict__ src,
                                                  const int* __restrict__ dst,
                                                  const int* __restrict__ hoff,
                                                  uint32_t* __restrict__ packed) {
    __shared__ int loff[NBUCKET];
    int blk = blockIdx.x, t = threadIdx.x;
    for (int i = t; i < NBUCKET; i += 256) loff[i] = hoff[i * NBE + blk];
    __syncthreads();
    int e0 = blk * ECHUNK;
    int e1 = e0 + ECHUNK; if (e1 > N_EDGES) e1 = N_EDGES;
    for (int e = e0 + t; e < e1; e += 256) {
        int d = dst[e];
        int pos = atomicAdd(&loff[d >> 8], 1);
        packed[pos] = ((uint32_t)src[e] << 8) | (uint32_t)(d & 255);
    }
}

// per-bucket node histogram -> deg, per-node padded (mult-of-8) excl scan -> ppos
__global__ __launch_bounds__(256) void bhist_k(const uint32_t* __restrict__ packed,
                                               const int* __restrict__ hoff,
                                               int* __restrict__ deg,
                                               int* __restrict__ ppos,
                                               int* __restrict__ pbtot) {
    __shared__ int lhist[256];
    __shared__ int ssc[256];
    int b = blockIdx.x, t = threadIdx.x;
    int base = hoff[b * NBE];
    int next = (b + 1 < NBUCKET) ? hoff[(b + 1) * NBE] : N_EDGES;
    int cnt = next - base;
    lhist[t] = 0;
    __syncthreads();
    for (int i = t; i < cnt; i += 256) atomicAdd(&lhist[packed[base + i] & 255u], 1);
    __syncthreads();
    int d = lhist[t];
    int pd = (d + 7) & ~7;
    ssc[t] = pd;
    __syncthreads();
    int val = pd;
    for (int off = 1; off < 256; off <<= 1) {
        int x = (t >= off) ? ssc[t - off] : 0;
        __syncthreads();
        val += x;
        ssc[t] = val;
        __syncthreads();
    }
    int node = (b << 8) + t;
    if (node < N_NODES) { deg[node] = d; ppos[node] = val - pd; }
    if (t == 255) pbtot[b] = val;
}

// exclusive scan of 391 padded bucket totals
__global__ void pscan_k(const int* __restrict__ pbtot, int* __restrict__ pbase) {
    __shared__ int sm[512];
    int t = threadIdx.x;
    int v = (t < NBUCKET) ? pbtot[t] : 0;
    sm[t] = v;
    __syncthreads();
    int val = v;
    for (int off = 1; off < 512; off <<= 1) {
        int x = (t >= off) ? sm[t - off] : 0;
        __syncthreads();
        val += x;
        sm[t] = val;
        __syncthreads();
    }
    if (t < NBUCKET) pbase[t] = val - v;
}

// padded CSR scatter: sentinel-filled pads, per-node padded row starts
#define LCAP2 8192
__global__ __launch_bounds__(256) void pscatter_k(const uint32_t* __restrict__ packed,
                                                  const int* __restrict__ hoff,
                                                  const int* __restrict__ ppos,
                                                  const int* __restrict__ pbtot,
                                                  const int* __restrict__ pbase,
                                                  int* __restrict__ csr,
                                                  int* __restrict__ prowst) {
    __shared__ int lcur[256];
    __shared__ int lcsr[LCAP2];
    int b = blockIdx.x, t = threadIdx.x;
    int base = hoff[b * NBE];
    int next = (b + 1 < NBUCKET) ? hoff[(b + 1) * NBE] : N_EDGES;
    int cnt = next - base;
    int pb = pbase[b];
    int pcnt = pbtot[b];
    int node = (b << 8) + t;
    int pp = (node < N_NODES) ? ppos[node] : 0;
    lcur[t] = pp;
    if (node < N_NODES) prowst[node] = pb + pp;
    __syncthreads();
    if (pcnt <= LCAP2) {
        for (int i = t; i < pcnt; i += 256) lcsr[i] = SENTINEL;
        __syncthreads();
        for (int i = t; i < cnt; i += 256) {
            uint32_t pk = packed[base + i];
            int pos = atomicAdd(&lcur[pk & 255u], 1);
            lcsr[pos] = (int)(pk >> 8);
        }
        __syncthreads();
        for (int i = t; i < pcnt; i += 256) csr[pb + i] = lcsr[i];
    } else {  // statistically unreachable
        for (int i = t; i < pcnt; i += 256) csr[pb + i] = SENTINEL;
        __syncthreads();
        for (int i = t; i < cnt; i += 256) {
            uint32_t pk = packed[base + i];
            int pos = atomicAdd(&lcur[pk & 255u], 1);
            csr[pb + pos] = (int)(pk >> 8);
        }
    }
}

// ---------------- dtype prep: x -> bf16 copy (GEMM) + fp8 copy (gather) ----------------

__global__ void cast_x_k(const float* __restrict__ x, uint16_t* __restrict__ xb,
                         uint32_t* __restrict__ xf8) {
    int i = blockIdx.x * blockDim.x + threadIdx.x;   // 8 floats per thread
    if (blockIdx.x == 0 && threadIdx.x < 32)
        xf8[N_NODES * 32 + threadIdx.x] = 0u;        // sentinel zero row
    if (i >= N_NODES * IN_DIM / 8) return;
    const float4* xv = (const float4*)x;
    float4 v0 = xv[2 * i], v1 = xv[2 * i + 1];
    union { uint16_t u[8]; uint4 q; } o;
    o.u[0] = f_to_bf16(v0.x); o.u[1] = f_to_bf16(v0.y);
    o.u[2] = f_to_bf16(v0.z); o.u[3] = f_to_bf16(v0.w);
    o.u[4] = f_to_bf16(v1.x); o.u[5] = f_to_bf16(v1.y);
    o.u[6] = f_to_bf16(v1.z); o.u[7] = f_to_bf16(v1.w);
    ((uint4*)xb)[i] = o.q;
    int p0 = __builtin_amdgcn_cvt_pk_fp8_f32(v0.x, v0.y, 0, false);
    p0 = __builtin_amdgcn_cvt_pk_fp8_f32(v0.z, v0.w, p0, true);
    int p1 = __builtin_amdgcn_cvt_pk_fp8_f32(v1.x, v1.y, 0, false);
    p1 = __builtin_amdgcn_cvt_pk_fp8_f32(v1.z, v1.w, p1, true);
    uint2 w2; w2.x = (uint32_t)p0; w2.y = (uint32_t)p1;
    ((uint2*)xf8)[i] = w2;
}

__global__ void prep_w_k(const float* __restrict__ W1l, const float* __restrict__ W1r,
                         const float* __restrict__ W2l, const float* __restrict__ W2r,
                         uint16_t* __restrict__ wT1, uint16_t* __restrict__ wT2) {
    int i = blockIdx.x * blockDim.x + threadIdx.x;
    if (i < 128 * 256) {
        int n = i >> 8, k = i & 255;
        float v = (k < 128) ? W1l[k * 128 + n] : W1r[(k - 128) * 128 + n];
        wT1[i] = f_to_bf16(v);
    } else {
        int j = i - 128 * 256;
        if (j < 128 * 128) {
            int n = j >> 7, k = j & 127;
            float v = (n < 64) ? W2l[k * 64 + n] : W2r[k * 64 + (n - 64)];
            wT2[j] = f_to_bf16(v);
        }
    }
}

// ---------------- layer-1 mean aggregation: 2 nodes/wave, no shuffle epilogue ----
// half-wave (32 lanes) owns one node; lane covers 4 B of the 128 B fp8 row.
// 8 slots/iter = 8 neighbors per node per iteration; padded deg (mult of 8).

__global__ void aggregate_k(const int* __restrict__ csr, const int* __restrict__ prowst,
                            const int* __restrict__ deg,
                            const uint32_t* __restrict__ inf8, uint32_t* __restrict__ out2) {
    int gw = (blockIdx.x * blockDim.x + threadIdx.x) >> 6;
    int lane = threadIdx.x & 63;
    int c = lane & 31, p = lane >> 5;
    int node = 2 * gw + p;                 // grid exact: 50000 waves x 2 = 100000
    int start = prowst[node];
    int d = deg[node];
    int pd = (d + 7) & ~7;
    f32x2 s01 = (f32x2){0.f, 0.f}, s23 = (f32x2){0.f, 0.f};
    for (int j = 0; j < pd; j += 8) {
        uint32_t q[8];
#pragma unroll
        for (int u = 0; u < 8; u++) {
            int s = csr[start + j + u];
            q[u] = inf8[(s << 5) + c];
        }
#pragma unroll
        for (int u = 0; u < 8; u++) {
            s01 += __builtin_amdgcn_cvt_pk_f32_fp8((int)q[u], false);
            s23 += __builtin_amdgcn_cvt_pk_f32_fp8((int)q[u], true);
        }
    }
    float inv = 1.0f / (float)(d > 0 ? d : 1);
    uint2 o;
    o.x = pack_bf16x2(s01[0] * inv, s01[1] * inv);
    o.y = pack_bf16x2(s23[0] * inv, s23[1] * inv);
    ((uint2*)out2)[node * 32 + c] = o;     // full-wave store, 2 rows / instr
}

// ---------------- layer-1 GEMM: [aggr | x] (M x 256) @ wT1 (128 x 256)^T ----------------
// Block: 256 thr stages wT1 (64KB) in LDS (xor-swizzled); 4 waves x 64 rows = 256 rows.
// mfma_f32_16x16x32_bf16: A lane m=lane&15, k=quad*8+j ; C/D: col=lane&15, row=quad*4+reg

__global__ __launch_bounds__(256, 2) void gemm1_k(const uint16_t* __restrict__ ab,
                                                  const uint16_t* __restrict__ xb,
                                                  const uint16_t* __restrict__ wT1,
                                                  const float* __restrict__ b1,
                                                  uint16_t* __restrict__ hb) {
    __shared__ uint16_t lw[128 * 256];   // 64 KB
    int t = threadIdx.x;
    {   // stage: global chunk i = (row r = i>>5, chunk cc = i&31) -> lds chunk r*32 + (cc^(r&31))
        const uint4* gsrc = (const uint4*)wT1;
        uint4* ldst = (uint4*)lw;
        for (int i = t; i < 4096; i += 256) {
            int r = i >> 5, cc = i & 31;
            ldst[(r << 5) + (cc ^ (r & 31))] = gsrc[i];
        }
    }
    __syncthreads();

    int wave = t >> 6;
    int lane = t & 63;
    int m0 = blockIdx.x * 256 + wave * 64;
    int mr = lane & 15, quad = lane >> 4;

    const uint16_t* A1[4];
    const uint16_t* A2[4];
#pragma unroll
    for (int s = 0; s < 4; s++) {
        int row = m0 + s * 16 + mr;
        if (row > N_NODES - 1) row = N_NODES - 1;   // clamp (stores still guarded)
        A1[s] = ab + (size_t)row * 128 + quad * 8;
        A2[s] = xb + (size_t)row * 128 + quad * 8;
    }

    f32x4 acc[8][4];
#pragma unroll
    for (int nt = 0; nt < 8; nt++)
#pragma unroll
        for (int s = 0; s < 4; s++) acc[nt][s] = (f32x4){0.f, 0.f, 0.f, 0.f};

#pragma unroll
    for (int kt = 0; kt < 8; kt++) {
        bf16x8 av[4];
#pragma unroll
        for (int s = 0; s < 4; s++) {
            const uint16_t* ap = (kt < 4) ? (A1[s] + kt * 32) : (A2[s] + (kt - 4) * 32);
            av[s] = *reinterpret_cast<const bf16x8*>(ap);
        }
#pragma unroll
        for (int nt = 0; nt < 8; nt++) {
            int brow = nt * 16 + mr;
            int chunk = kt * 4 + quad;
            const uint16_t* bp = lw + (brow << 8) + ((chunk ^ (brow & 31)) << 3);
            bf16x8 b = *reinterpret_cast<const bf16x8*>(bp);
#pragma unroll
            for (int s = 0; s < 4; s++)
                acc[nt][s] = __builtin_amdgcn_mfma_f32_16x16x32_bf16(av[s], b, acc[nt][s], 0, 0, 0);
        }
    }

#pragma unroll
    for (int nt = 0; nt < 8; nt++) {
        int col = nt * 16 + mr;
        float bias = b1[col];
#pragma unroll
        for (int s = 0; s < 4; s++) {
#pragma unroll
            for (int r = 0; r < 4; r++) {
                int row = m0 + s * 16 + quad * 4 + r;
                if (row < N_NODES) {
                    float v = acc[nt][s][r] + bias;
                    v = v > 0.f ? v : 0.f;
                    hb[(size_t)row * 128 + col] = f_to_bf16(v);
                }
            }
        }
    }
}

// ---------------- layer-2 GEMM: h (M x 128) @ wT2 (128 x 128)^T ----------------
// cols 0..63 -> g = h@W2l (fp8); cols 64..127 -> z = h@W2r + b2 (fp32)

__global__ __launch_bounds__(256, 2) void gemm2_k(const uint16_t* __restrict__ hb,
                                                  const uint16_t* __restrict__ wT2,
                                                  const float* __restrict__ b2,
                                                  uint8_t* __restrict__ g,
                                                  float* __restrict__ z) {
    __shared__ uint16_t lw[128 * 128];   // 32 KB
    int t = threadIdx.x;
    if (blockIdx.x == 0 && t < 16)
        ((uint32_t*)(g + (size_t)N_NODES * 64))[t] = 0u;  // sentinel zero row
    {   // stage: chunk i = (r = i>>4, cc = i&15) -> lds chunk r*16 + (cc^(r&15))
        const uint4* gsrc = (const uint4*)wT2;
        uint4* ldst = (uint4*)lw;
        for (int i = t; i < 2048; i += 256) {
            int r = i >> 4, cc = i & 15;
            ldst[(r << 4) + (cc ^ (r & 15))] = gsrc[i];
        }
    }
    __syncthreads();

    int wave = t >> 6;
    int lane = t & 63;
    int m0 = blockIdx.x * 256 + wave * 64;
    int mr = lane & 15, quad = lane >> 4;

    const uint16_t* A[4];
#pragma unroll
    for (int s = 0; s < 4; s++) {
        int row = m0 + s * 16 + mr;
        if (row > N_NODES - 1) row = N_NODES - 1;
        A[s] = hb + (size_t)row * 128 + quad * 8;
    }

    f32x4 acc[8][4];
#pragma unroll
    for (int nt = 0; nt < 8; nt++)
#pragma unroll
        for (int s = 0; s < 4; s++) acc[nt][s] = (f32x4){0.f, 0.f, 0.f, 0.f};

#pragma unroll
    for (int kt = 0; kt < 4; kt++) {
        bf16x8 av[4];
#pragma unroll
        for (int s = 0; s < 4; s++)
            av[s] = *reinterpret_cast<const bf16x8*>(A[s] + kt * 32);
#pragma unroll
        for (int nt = 0; nt < 8; nt++) {
            int brow = nt * 16 + mr;
            int chunk = kt * 4 + quad;
            const uint16_t* bp = lw + (brow << 7) + ((chunk ^ (brow & 15)) << 3);
            bf16x8 b = *reinterpret_cast<const bf16x8*>(bp);
#pragma unroll
            for (int s = 0; s < 4; s++)
                acc[nt][s] = __builtin_amdgcn_mfma_f32_16x16x32_bf16(av[s], b, acc[nt][s], 0, 0, 0);
        }
    }

#pragma unroll
    for (int nt = 0; nt < 8; nt++) {
        int col = nt * 16 + mr;
#pragma unroll
        for (int s = 0; s < 4; s++) {
#pragma unroll
            for (int r = 0; r < 4; r++) {
                int row = m0 + s * 16 + quad * 4 + r;
                if (row < N_NODES) {
                    if (nt < 4) {
                        float v = acc[nt][s][r];
                        int pk = __builtin_amdgcn_cvt_pk_fp8_f32(v, v, 0, false);
                        g[(size_t)row * 64 + col] = (uint8_t)(pk & 0xff);
                    } else {
                        z[(size_t)row * 64 + (col - 64)] = acc[nt][s][r] + b2[col - 64];
                    }
                }
            }
        }
    }
}

// ---------------- layer-2 aggregation: 4 nodes/wave, no shuffle epilogue ----
// quarter-wave (16 lanes) owns one node; lane covers 4 B of the 64 B fp8 row.

__global__ void agg2_k(const int* __restrict__ csr, const int* __restrict__ prowst,
                       const int* __restrict__ deg,
                       const uint32_t* __restrict__ g4, const float* __restrict__ z,
                       float* __restrict__ out) {
    int gw = (blockIdx.x * blockDim.x + threadIdx.x) >> 6;
    int lane = threadIdx.x & 63;
    int c = lane & 15, q4 = lane >> 4;
    int node = 4 * gw + q4;                // grid exact: 25000 waves x 4 = 100000
    int start = prowst[node];
    int d = deg[node];
    int pd = (d + 7) & ~7;
    f32x2 s01 = (f32x2){0.f, 0.f}, s23 = (f32x2){0.f, 0.f};
    for (int j = 0; j < pd; j += 8) {
        uint32_t q[8];
#pragma unroll
        for (int u = 0; u < 8; u++) {
            int s = csr[start + j + u];
            q[u] = g4[(s << 4) + c];
        }
#pragma unroll
        for (int u = 0; u < 8; u++) {
            s01 += __builtin_amdgcn_cvt_pk_f32_fp8((int)q[u], false);
            s23 += __builtin_amdgcn_cvt_pk_f32_fp8((int)q[u], true);
        }
    }
    float inv = 1.0f / (float)(d > 0 ? d : 1);
    float4 zz = ((const float4*)z)[node * 16 + c];
    float4 o;
    o.x = s01[0] * inv + zz.x;
    o.y = s01[1] * inv + zz.y;
    o.z = s23[0] * inv + zz.z;
    o.w = s23[1] * inv + zz.w;
    ((float4*)out)[node * 16 + c] = o;     // full-wave store, 4 rows / instr
}

// ---------------- launch ----------------

extern "C" void kernel_launch(void* const* d_in, const int* in_sizes, int n_in,
                              void* d_out, int out_size, void* d_ws, size_t ws_size,
                              hipStream_t stream) {
    const float* x   = (const float*)d_in[0];
    const int*  ei   = (const int*)d_in[1];
    const float* W1l = (const float*)d_in[2];
    const float* b1  = (const float*)d_in[3];
    const float* W1r = (const float*)d_in[4];
    const float* W2l = (const float*)d_in[5];
    const float* b2  = (const float*)d_in[6];
    const float* W2r = (const float*)d_in[7];
    float* out = (float*)d_out;

    const int* srcv = ei;            // edge_index[0]
    const int* dstv = ei + N_EDGES;  // edge_index[1]

    char* ws = (char*)d_ws;
    int*      deg      = (int*)(ws + 0);              // 100000 ints
    int*      prowst   = (int*)(ws + 401408);         // 100000 ints (padded row starts)
    int*      ppos     = (int*)(ws + 802816);         // 100000 ints
    int*      partials = (int*)(ws + 1204224);        // 150 ints
    int*      pbtot    = (int*)(ws + 1205248);        // 391 ints
    int*      pbase    = (int*)(ws + 1207296);        // 391 ints
    int*      csr      = (int*)(ws + 1209344);        // padded csr (~2.0M ints, cap 12.6MB)
    uint16_t* wT1      = (uint16_t*)(ws + 13809664);  // 64 KB
    uint16_t* wT2      = (uint16_t*)(ws + 13875200);  // 32 KB
    uint16_t* xb       = (uint16_t*)(ws + 13907968);  // 25.6 MB -> 39507968
    char*     abreg    = (ws + 39507968);             // 25.6 MB region -> 65107968
    uint16_t* hb       = (uint16_t*)(ws + 65107968);  // 25.6 MB -> 90707968
    // layer-1: abreg = bf16 aggregate; layer-2 reuse: z (fp32, 25.6MB) = abreg, g (fp8) = xb
    uint16_t* ab       = (uint16_t*)abreg;
    float*    z        = (float*)abreg;               // written by gemm2 after ab last read
    uint8_t*  g        = (uint8_t*)xb;                // written by gemm2 after xb last read
    // aliases into hb region (consumed before gemm1 writes hb; stream-ordered):
    uint32_t* packed   = (uint32_t*)hb;                       // 6.4 MB
    int*      hoff     = (int*)(ws + 65107968 + 6400000);     // 611 KB
    uint32_t* xf8      = (uint32_t*)(ws + 65107968 + 7013376);// 12.8 MB + 128

    // graph build (no global atomics), padded CSR
    hist1_k<<<NBE, 256, 0, stream>>>(dstv, hoff);
    scan1_k<<<NB_SCAN, 256, 0, stream>>>(hoff, partials, HM);
    scan2_k<<<1, 256, 0, stream>>>(partials, NB_SCAN);
    scan3_k<<<(HM + 255) / 256, 256, 0, stream>>>(hoff, partials, HM);
    scatter2_k<<<NBE, 256, 0, stream>>>(srcv, dstv, hoff, packed);
    bhist_k<<<NBUCKET, 256, 0, stream>>>(packed, hoff, deg, ppos, pbtot);
    pscan_k<<<1, 512, 0, stream>>>(pbtot, pbase);
    pscatter_k<<<NBUCKET, 256, 0, stream>>>(packed, hoff, ppos, pbtot, pbase, csr, prowst);

    // dtype prep
    cast_x_k<<<6250, 256, 0, stream>>>(x, xb, xf8);
    prep_w_k<<<192, 256, 0, stream>>>(W1l, W1r, W2l, W2r, wT1, wT2);

    // layer 1: aggr(x_fp8) -> ab(bf16) ; h = relu([ab|x] @ wT1^T + b1) -> hb
    aggregate_k<<<12500, 256, 0, stream>>>(csr, prowst, deg, xf8, (uint32_t*)ab);
    gemm1_k<<<391, 256, 0, stream>>>(ab, xb, wT1, b1, hb);

    // layer 2: [g|z] = h @ [W2l|W2r] (+b2 on z), g fp8 / z fp32 ; out = mean-aggr(g) + z
    gemm2_k<<<391, 256, 0, stream>>>(hb, wT2, b2, g, z);
    agg2_k<<<6250, 256, 0, stream>>>(csr, prowst, deg, (const uint32_t*)g, z, out);
}

// Round 9
// 269.230 us; speedup vs baseline: 3.7018x; 1.0033x over previous
//
#include <hip/hip_runtime.h>
#include <hip/hip_bf16.h>
#include <stdint.h>

#define N_NODES 100000
#define N_EDGES 1600000
#define IN_DIM 128
#define HID_DIM 128
#define OUT_DIM 64
#define NBUCKET 391   // ceil(N_NODES/256), bucket = dst>>8
#define NBE 391       // edge blocks, 4096 edges each
#define ECHUNK 4096
#define HM (NBUCKET * NBE)          // 152881 hist entries
#define NB_SCAN 150                 // ceil(HM/1024)
#define SENTINEL N_NODES            // padded-slot src -> zero row
#define PCAP 6144                   // fixed padded bucket capacity (+32 sigma)

typedef __bf16 bf16x8 __attribute__((ext_vector_type(8)));
typedef float f32x4 __attribute__((ext_vector_type(4)));
typedef float f32x2 __attribute__((ext_vector_type(2)));

__device__ __forceinline__ uint16_t f_to_bf16(float f) {
    uint32_t u = __float_as_uint(f);
    u += 0x7fffu + ((u >> 16) & 1u);   // round-to-nearest-even
    return (uint16_t)(u >> 16);
}
__device__ __forceinline__ uint32_t pack_bf16x2(float lo, float hi) {
    return (uint32_t)f_to_bf16(lo) | ((uint32_t)f_to_bf16(hi) << 16);
}

// ---------------- fused prep: edge histogram + x casts + weight transpose ----------------
// blocks [0, NBE): per-block bucket histogram of dst
// blocks [NBE, NBE+6250): cast x -> bf16 xb + fp8 xf8
// blocks [NBE+6250, NBE+6250+192): transpose/cast weights

__global__ __launch_bounds__(256) void prep_k(const int* __restrict__ dst,
                                              const float* __restrict__ x,
                                              const float* __restrict__ W1l,
                                              const float* __restrict__ W1r,
                                              const float* __restrict__ W2l,
                                              const float* __restrict__ W2r,
                                              int* __restrict__ hist,
                                              uint16_t* __restrict__ xb,
                                              uint32_t* __restrict__ xf8,
                                              uint16_t* __restrict__ wT1,
                                              uint16_t* __restrict__ wT2) {
    __shared__ int lh[NBUCKET];
    int blk = blockIdx.x, t = threadIdx.x;
    if (blk < NBE) {
        for (int i = t; i < NBUCKET; i += 256) lh[i] = 0;
        __syncthreads();
        int e0 = blk * ECHUNK;
        int e1 = e0 + ECHUNK; if (e1 > N_EDGES) e1 = N_EDGES;
        for (int e = e0 + t; e < e1; e += 256) atomicAdd(&lh[dst[e] >> 8], 1);
        __syncthreads();
        for (int i = t; i < NBUCKET; i += 256) hist[i * NBE + blk] = lh[i];
    } else if (blk < NBE + 6250) {
        int i = (blk - NBE) * 256 + t;   // 8 floats per thread
        if (blk == NBE && t < 32) xf8[N_NODES * 32 + t] = 0u;  // sentinel zero row
        if (i >= N_NODES * IN_DIM / 8) return;
        const float4* xv = (const float4*)x;
        float4 v0 = xv[2 * i], v1 = xv[2 * i + 1];
        union { uint16_t u[8]; uint4 q; } o;
        o.u[0] = f_to_bf16(v0.x); o.u[1] = f_to_bf16(v0.y);
        o.u[2] = f_to_bf16(v0.z); o.u[3] = f_to_bf16(v0.w);
        o.u[4] = f_to_bf16(v1.x); o.u[5] = f_to_bf16(v1.y);
        o.u[6] = f_to_bf16(v1.z); o.u[7] = f_to_bf16(v1.w);
        ((uint4*)xb)[i] = o.q;
        int p0 = __builtin_amdgcn_cvt_pk_fp8_f32(v0.x, v0.y, 0, false);
        p0 = __builtin_amdgcn_cvt_pk_fp8_f32(v0.z, v0.w, p0, true);
        int p1 = __builtin_amdgcn_cvt_pk_fp8_f32(v1.x, v1.y, 0, false);
        p1 = __builtin_amdgcn_cvt_pk_fp8_f32(v1.z, v1.w, p1, true);
        uint2 w2; w2.x = (uint32_t)p0; w2.y = (uint32_t)p1;
        ((uint2*)xf8)[i] = w2;
    } else {
        int i = (blk - NBE - 6250) * 256 + t;
        if (i < 128 * 256) {
            int n = i >> 8, k = i & 255;
            float v = (k < 128) ? W1l[k * 128 + n] : W1r[(k - 128) * 128 + n];
            wT1[i] = f_to_bf16(v);
        } else {
            int j = i - 128 * 256;
            if (j < 128 * 128) {
                int n = j >> 7, k = j & 127;
                float v = (n < 64) ? W2l[k * 64 + n] : W2r[k * 64 + (n - 64)];
                wT2[j] = f_to_bf16(v);
            }
        }
    }
}

// ---------------- scan of the 391x391 hist matrix ----------------

__global__ void scan1_k(int* __restrict__ data, int* __restrict__ partials, int n) {
    __shared__ int sm[256];
    int tid = threadIdx.x;
    int base = blockIdx.x * 1024 + tid * 4;
    int v0 = 0, v1 = 0, v2 = 0, v3 = 0;
    if (base + 0 < n) v0 = data[base + 0];
    if (base + 1 < n) v1 = data[base + 1];
    if (base + 2 < n) v2 = data[base + 2];
    if (base + 3 < n) v3 = data[base + 3];
    int tot = v0 + v1 + v2 + v3;
    sm[tid] = tot;
    __syncthreads();
    int val = tot;
    for (int off = 1; off < 256; off <<= 1) {
        int x = (tid >= off) ? sm[tid - off] : 0;
        __syncthreads();
        val += x;
        sm[tid] = val;
        __syncthreads();
    }
    int excl = val - tot;
    if (tid == 255) partials[blockIdx.x] = val;
    if (base + 0 < n) data[base + 0] = excl;
    if (base + 1 < n) data[base + 1] = excl + v0;
    if (base + 2 < n) data[base + 2] = excl + v0 + v1;
    if (base + 3 < n) data[base + 3] = excl + v0 + v1 + v2;
}

// fused: re-scan the 150 block partials in LDS, then add to elements
__global__ void scan3_k(int* __restrict__ data, const int* __restrict__ partials, int n) {
    __shared__ int sm[256];
    __shared__ int sp[256];
    int t = threadIdx.x;
    int v = (t < NB_SCAN) ? partials[t] : 0;
    sm[t] = v;
    __syncthreads();
    int val = v;
    for (int off = 1; off < 256; off <<= 1) {
        int x = (t >= off) ? sm[t - off] : 0;
        __syncthreads();
        val += x;
        sm[t] = val;
        __syncthreads();
    }
    sp[t] = val - v;   // exclusive
    __syncthreads();
    int i = blockIdx.x * 256 + t;
    if (i < n) data[i] += sp[i >> 10];
}

__global__ __launch_bounds__(256) void scatter2_k(const int* __restrict__ src,
                                                  const int* __restrict__ dst,
                                                  const int* __restrict__ hoff,
                                                  uint32_t* __restrict__ packed) {
    __shared__ int loff[NBUCKET];
    int blk = blockIdx.x, t = threadIdx.x;
    for (int i = t; i < NBUCKET; i += 256) loff[i] = hoff[i * NBE + blk];
    __syncthreads();
    int e0 = blk * ECHUNK;
    int e1 = e0 + ECHUNK; if (e1 > N_EDGES) e1 = N_EDGES;
    for (int e = e0 + t; e < e1; e += 256) {
        int d = dst[e];
        int pos = atomicAdd(&loff[d >> 8], 1);
        packed[pos] = ((uint32_t)src[e] << 8) | (uint32_t)(d & 255);
    }
}

// ---------------- fused finalize: hist + padded scan + sentinel CSR, fixed-cap buckets ---
// bucket b owns csr[b*PCAP .. b*PCAP+PCAP); emits deg[] and prowst[].

__global__ __launch_bounds__(256) void finalize_k(const uint32_t* __restrict__ packed,
                                                  const int* __restrict__ hoff,
                                                  int* __restrict__ csr,
                                                  int* __restrict__ deg,
                                                  int* __restrict__ prowst) {
    __shared__ int lhist[256];
    __shared__ int ssc[256];
    __shared__ int lcur[256];
    __shared__ int s_pcnt;
    __shared__ uint32_t lpk[PCAP];
    __shared__ int lcsr[PCAP];
    int b = blockIdx.x, t = threadIdx.x;
    int base = hoff[b * NBE];
    int next = (b + 1 < NBUCKET) ? hoff[(b + 1) * NBE] : N_EDGES;
    int cnt = next - base;
    lhist[t] = 0;
    __syncthreads();
    bool fit = (cnt <= PCAP);
    if (fit) {
        for (int i = t; i < cnt; i += 256) {
            uint32_t pk = packed[base + i];
            lpk[i] = pk;
            atomicAdd(&lhist[pk & 255u], 1);
        }
    } else {
        for (int i = t; i < cnt; i += 256) atomicAdd(&lhist[packed[base + i] & 255u], 1);
    }
    __syncthreads();
    int d = lhist[t];
    int pd = (d + 7) & ~7;
    ssc[t] = pd;
    __syncthreads();
    int val = pd;
    for (int off = 1; off < 256; off <<= 1) {
        int x = (t >= off) ? ssc[t - off] : 0;
        __syncthreads();
        val += x;
        ssc[t] = val;
        __syncthreads();
    }
    int excl = val - pd;
    lcur[t] = excl;
    if (t == 255) s_pcnt = val;
    int node = (b << 8) + t;
    if (node < N_NODES) { deg[node] = d; prowst[node] = b * PCAP + excl; }
    __syncthreads();
    int pcnt = s_pcnt;
    int cbase = b * PCAP;
    if (fit && pcnt <= PCAP) {
        for (int i = t; i < pcnt; i += 256) lcsr[i] = SENTINEL;
        __syncthreads();
        for (int i = t; i < cnt; i += 256) {
            uint32_t pk = lpk[i];
            int pos = atomicAdd(&lcur[pk & 255u], 1);
            lcsr[pos] = (int)(pk >> 8);
        }
        __syncthreads();
        for (int i = t; i < pcnt; i += 256) csr[cbase + i] = lcsr[i];
    } else {  // statistically unreachable (+32 sigma); stays within slice
        int lim = pcnt < PCAP ? pcnt : PCAP;
        for (int i = t; i < lim; i += 256) csr[cbase + i] = SENTINEL;
        __syncthreads();
        for (int i = t; i < cnt; i += 256) {
            uint32_t pk = packed[base + i];
            int pos = atomicAdd(&lcur[pk & 255u], 1);
            if (pos < PCAP) csr[cbase + pos] = (int)(pk >> 8);
        }
    }
}

// ---------------- layer-1 mean aggregation: 2 nodes/wave, no shuffle epilogue ----
// half-wave (32 lanes) owns one node; lane covers 4 B of the 128 B fp8 row.

__global__ void aggregate_k(const int* __restrict__ csr, const int* __restrict__ prowst,
                            const int* __restrict__ deg,
                            const uint32_t* __restrict__ inf8, uint32_t* __restrict__ out2) {
    int gw = (blockIdx.x * blockDim.x + threadIdx.x) >> 6;
    int lane = threadIdx.x & 63;
    int c = lane & 31, p = lane >> 5;
    int node = 2 * gw + p;                 // grid exact: 50000 waves x 2 = 100000
    int start = prowst[node];
    int d = deg[node];
    int pd = (d + 7) & ~7;
    f32x2 s01 = (f32x2){0.f, 0.f}, s23 = (f32x2){0.f, 0.f};
    for (int j = 0; j < pd; j += 8) {
        uint32_t q[8];
#pragma unroll
        for (int u = 0; u < 8; u++) {
            int s = csr[start + j + u];
            q[u] = inf8[(s << 5) + c];
        }
#pragma unroll
        for (int u = 0; u < 8; u++) {
            s01 += __builtin_amdgcn_cvt_pk_f32_fp8((int)q[u], false);
            s23 += __builtin_amdgcn_cvt_pk_f32_fp8((int)q[u], true);
        }
    }
    float inv = 1.0f / (float)(d > 0 ? d : 1);
    uint2 o;
    o.x = pack_bf16x2(s01[0] * inv, s01[1] * inv);
    o.y = pack_bf16x2(s23[0] * inv, s23[1] * inv);
    ((uint2*)out2)[node * 32 + c] = o;     // full-wave store, 2 rows / instr
}

// ---------------- layer-1 GEMM: [aggr | x] (M x 256) @ wT1 (128 x 256)^T ----------------
// Block: 256 thr stages wT1 (64KB) in LDS (xor-swizzled); 4 waves x 64 rows = 256 rows.
// mfma_f32_16x16x32_bf16: A lane m=lane&15, k=quad*8+j ; C/D: col=lane&15, row=quad*4+reg

__global__ __launch_bounds__(256, 2) void gemm1_k(const uint16_t* __restrict__ ab,
                                                  const uint16_t* __restrict__ xb,
                                                  const uint16_t* __restrict__ wT1,
                                                  const float* __restrict__ b1,
                                                  uint16_t* __restrict__ hb) {
    __shared__ uint16_t lw[128 * 256];   // 64 KB
    int t = threadIdx.x;
    {   // stage: global chunk i = (row r = i>>5, chunk cc = i&31) -> lds chunk r*32 + (cc^(r&31))
        const uint4* gsrc = (const uint4*)wT1;
        uint4* ldst = (uint4*)lw;
        for (int i = t; i < 4096; i += 256) {
            int r = i >> 5, cc = i & 31;
            ldst[(r << 5) + (cc ^ (r & 31))] = gsrc[i];
        }
    }
    __syncthreads();

    int wave = t >> 6;
    int lane = t & 63;
    int m0 = blockIdx.x * 256 + wave * 64;
    int mr = lane & 15, quad = lane >> 4;

    const uint16_t* A1[4];
    const uint16_t* A2[4];
#pragma unroll
    for (int s = 0; s < 4; s++) {
        int row = m0 + s * 16 + mr;
        if (row > N_NODES - 1) row = N_NODES - 1;   // clamp (stores still guarded)
        A1[s] = ab + (size_t)row * 128 + quad * 8;
        A2[s] = xb + (size_t)row * 128 + quad * 8;
    }

    f32x4 acc[8][4];
#pragma unroll
    for (int nt = 0; nt < 8; nt++)
#pragma unroll
        for (int s = 0; s < 4; s++) acc[nt][s] = (f32x4){0.f, 0.f, 0.f, 0.f};

#pragma unroll
    for (int kt = 0; kt < 8; kt++) {
        bf16x8 av[4];
#pragma unroll
        for (int s = 0; s < 4; s++) {
            const uint16_t* ap = (kt < 4) ? (A1[s] + kt * 32) : (A2[s] + (kt - 4) * 32);
            av[s] = *reinterpret_cast<const bf16x8*>(ap);
        }
#pragma unroll
        for (int nt = 0; nt < 8; nt++) {
            int brow = nt * 16 + mr;
            int chunk = kt * 4 + quad;
            const uint16_t* bp = lw + (brow << 8) + ((chunk ^ (brow & 31)) << 3);
            bf16x8 b = *reinterpret_cast<const bf16x8*>(bp);
#pragma unroll
            for (int s = 0; s < 4; s++)
                acc[nt][s] = __builtin_amdgcn_mfma_f32_16x16x32_bf16(av[s], b, acc[nt][s], 0, 0, 0);
        }
    }

#pragma unroll
    for (int nt = 0; nt < 8; nt++) {
        int col = nt * 16 + mr;
        float bias = b1[col];
#pragma unroll
        for (int s = 0; s < 4; s++) {
#pragma unroll
            for (int r = 0; r < 4; r++) {
                int row = m0 + s * 16 + quad * 4 + r;
                if (row < N_NODES) {
                    float v = acc[nt][s][r] + bias;
                    v = v > 0.f ? v : 0.f;
                    hb[(size_t)row * 128 + col] = f_to_bf16(v);
                }
            }
        }
    }
}

// ---------------- layer-2 GEMM: h (M x 128) @ wT2 (128 x 128)^T ----------------
// cols 0..63 -> g = h@W2l (fp8); cols 64..127 -> z = h@W2r + b2 (fp32)

__global__ __launch_bounds__(256, 2) void gemm2_k(const uint16_t* __restrict__ hb,
                                                  const uint16_t* __restrict__ wT2,
                                                  const float* __restrict__ b2,
                                                  uint8_t* __restrict__ g,
                                                  float* __restrict__ z) {
    __shared__ uint16_t lw[128 * 128];   // 32 KB
    int t = threadIdx.x;
    if (blockIdx.x == 0 && t < 16)
        ((uint32_t*)(g + (size_t)N_NODES * 64))[t] = 0u;  // sentinel zero row
    {   // stage: chunk i = (r = i>>4, cc = i&15) -> lds chunk r*16 + (cc^(r&15))
        const uint4* gsrc = (const uint4*)wT2;
        uint4* ldst = (uint4*)lw;
        for (int i = t; i < 2048; i += 256) {
            int r = i >> 4, cc = i & 15;
            ldst[(r << 4) + (cc ^ (r & 15))] = gsrc[i];
        }
    }
    __syncthreads();

    int wave = t >> 6;
    int lane = t & 63;
    int m0 = blockIdx.x * 256 + wave * 64;
    int mr = lane & 15, quad = lane >> 4;

    const uint16_t* A[4];
#pragma unroll
    for (int s = 0; s < 4; s++) {
        int row = m0 + s * 16 + mr;
        if (row > N_NODES - 1) row = N_NODES - 1;
        A[s] = hb + (size_t)row * 128 + quad * 8;
    }

    f32x4 acc[8][4];
#pragma unroll
    for (int nt = 0; nt < 8; nt++)
#pragma unroll
        for (int s = 0; s < 4; s++) acc[nt][s] = (f32x4){0.f, 0.f, 0.f, 0.f};

#pragma unroll
    for (int kt = 0; kt < 4; kt++) {
        bf16x8 av[4];
#pragma unroll
        for (int s = 0; s < 4; s++)
            av[s] = *reinterpret_cast<const bf16x8*>(A[s] + kt * 32);
#pragma unroll
        for (int nt = 0; nt < 8; nt++) {
            int brow = nt * 16 + mr;
            int chunk = kt * 4 + quad;
            const uint16_t* bp = lw + (brow << 7) + ((chunk ^ (brow & 15)) << 3);
            bf16x8 b = *reinterpret_cast<const bf16x8*>(bp);
#pragma unroll
            for (int s = 0; s < 4; s++)
                acc[nt][s] = __builtin_amdgcn_mfma_f32_16x16x32_bf16(av[s], b, acc[nt][s], 0, 0, 0);
        }
    }

#pragma unroll
    for (int nt = 0; nt < 8; nt++) {
        int col = nt * 16 + mr;
#pragma unroll
        for (int s = 0; s < 4; s++) {
#pragma unroll
            for (int r = 0; r < 4; r++) {
                int row = m0 + s * 16 + quad * 4 + r;
                if (row < N_NODES) {
                    if (nt < 4) {
                        float v = acc[nt][s][r];
                        int pk = __builtin_amdgcn_cvt_pk_fp8_f32(v, v, 0, false);
                        g[(size_t)row * 64 + col] = (uint8_t)(pk & 0xff);
                    } else {
                        z[(size_t)row * 64 + (col - 64)] = acc[nt][s][r] + b2[col - 64];
                    }
                }
            }
        }
    }
}

// ---------------- layer-2 aggregation: 4 nodes/wave, no shuffle epilogue ----
// quarter-wave (16 lanes) owns one node; lane covers 4 B of the 64 B fp8 row.

__global__ void agg2_k(const int* __restrict__ csr, const int* __restrict__ prowst,
                       const int* __restrict__ deg,
                       const uint32_t* __restrict__ g4, const float* __restrict__ z,
                       float* __restrict__ out) {
    int gw = (blockIdx.x * blockDim.x + threadIdx.x) >> 6;
    int lane = threadIdx.x & 63;
    int c = lane & 15, q4 = lane >> 4;
    int node = 4 * gw + q4;                // grid exact: 25000 waves x 4 = 100000
    int start = prowst[node];
    int d = deg[node];
    int pd = (d + 7) & ~7;
    f32x2 s01 = (f32x2){0.f, 0.f}, s23 = (f32x2){0.f, 0.f};
    for (int j = 0; j < pd; j += 8) {
        uint32_t q[8];
#pragma unroll
        for (int u = 0; u < 8; u++) {
            int s = csr[start + j + u];
            q[u] = g4[(s << 4) + c];
        }
#pragma unroll
        for (int u = 0; u < 8; u++) {
            s01 += __builtin_amdgcn_cvt_pk_f32_fp8((int)q[u], false);
            s23 += __builtin_amdgcn_cvt_pk_f32_fp8((int)q[u], true);
        }
    }
    float inv = 1.0f / (float)(d > 0 ? d : 1);
    float4 zz = ((const float4*)z)[node * 16 + c];
    float4 o;
    o.x = s01[0] * inv + zz.x;
    o.y = s01[1] * inv + zz.y;
    o.z = s23[0] * inv + zz.z;
    o.w = s23[1] * inv + zz.w;
    ((float4*)out)[node * 16 + c] = o;     // full-wave store, 4 rows / instr
}

// ---------------- launch ----------------

extern "C" void kernel_launch(void* const* d_in, const int* in_sizes, int n_in,
                              void* d_out, int out_size, void* d_ws, size_t ws_size,
                              hipStream_t stream) {
    const float* x   = (const float*)d_in[0];
    const int*  ei   = (const int*)d_in[1];
    const float* W1l = (const float*)d_in[2];
    const float* b1  = (const float*)d_in[3];
    const float* W1r = (const float*)d_in[4];
    const float* W2l = (const float*)d_in[5];
    const float* b2  = (const float*)d_in[6];
    const float* W2r = (const float*)d_in[7];
    float* out = (float*)d_out;

    const int* srcv = ei;            // edge_index[0]
    const int* dstv = ei + N_EDGES;  // edge_index[1]

    char* ws = (char*)d_ws;
    int*      deg      = (int*)(ws + 0);              // 100000 ints
    int*      prowst   = (int*)(ws + 401408);         // 100000 ints (padded row starts)
    int*      partials = (int*)(ws + 802816);         // 150 ints
    int*      csr      = (int*)(ws + 1209344);        // 391*PCAP ints = 9.6 MB -> 10818560
    uint16_t* wT1      = (uint16_t*)(ws + 13809664);  // 64 KB
    uint16_t* wT2      = (uint16_t*)(ws + 13875200);  // 32 KB
    uint16_t* xb       = (uint16_t*)(ws + 13907968);  // 25.6 MB -> 39507968
    char*     abreg    = (ws + 39507968);             // 25.6 MB region -> 65107968
    uint16_t* hb       = (uint16_t*)(ws + 65107968);  // 25.6 MB -> 90707968
    // layer-1: abreg = bf16 aggregate; layer-2 reuse: z (fp32, 25.6MB) = abreg, g (fp8) = xb
    uint16_t* ab       = (uint16_t*)abreg;
    float*    z        = (float*)abreg;               // written by gemm2 after ab last read
    uint8_t*  g        = (uint8_t*)xb;                // written by gemm2 after xb last read
    // aliases into hb region (consumed before gemm1 writes hb; stream-ordered):
    uint32_t* packed   = (uint32_t*)hb;                       // 6.4 MB
    int*      hoff     = (int*)(ws + 65107968 + 6400000);     // 611 KB
    uint32_t* xf8      = (uint32_t*)(ws + 65107968 + 7013376);// 12.8 MB + 128

    // fused prep: hist + casts + weight transpose (independent block ranges)
    prep_k<<<NBE + 6250 + 192, 256, 0, stream>>>(dstv, x, W1l, W1r, W2l, W2r,
                                                 hoff, xb, xf8, wT1, wT2);
    // scan hist matrix -> bucket-major global offsets
    scan1_k<<<NB_SCAN, 256, 0, stream>>>(hoff, partials, HM);
    scan3_k<<<(HM + 255) / 256, 256, 0, stream>>>(hoff, partials, HM);
    // partition edges into bucket-contiguous packed array
    scatter2_k<<<NBE, 256, 0, stream>>>(srcv, dstv, hoff, packed);
    // per-bucket padded CSR + deg + prowst (fixed-cap slices)
    finalize_k<<<NBUCKET, 256, 0, stream>>>(packed, hoff, csr, deg, prowst);

    // layer 1: aggr(x_fp8) -> ab(bf16) ; h = relu([ab|x] @ wT1^T + b1) -> hb
    aggregate_k<<<12500, 256, 0, stream>>>(csr, prowst, deg, xf8, (uint32_t*)ab);
    gemm1_k<<<391, 256, 0, stream>>>(ab, xb, wT1, b1, hb);

    // layer 2: [g|z] = h @ [W2l|W2r] (+b2 on z), g fp8 / z fp32 ; out = mean-aggr(g) + z
    gemm2_k<<<391, 256, 0, stream>>>(hb, wT2, b2, g, z);
    agg2_k<<<6250, 256, 0, stream>>>(csr, prowst, deg, (const uint32_t*)g, z, out);
}